// Round 4
// baseline (4676.229 us; speedup 1.0000x reference)
//
#include <hip/hip_runtime.h>

#define N_N 100000
#define N_E 1600000
#define N_G 256
#define F_IN 28
#define HEADS 4
#define CH 64
#define NEG 0.2f
#define LN_EPS 1e-5f

__device__ __forceinline__ float lrelu(float x) { return x > 0.f ? x : NEG * x; }

__device__ __forceinline__ float wsum(float v) {
#pragma unroll
  for (int o = 32; o > 0; o >>= 1) v += __shfl_xor(v, o, 64);
  return v;
}
__device__ __forceinline__ float wmax(float v) {
#pragma unroll
  for (int o = 32; o > 0; o >>= 1) v = fmaxf(v, __shfl_xor(v, o, 64));
  return v;
}
__device__ __forceinline__ int wsumi(int v) {
#pragma unroll
  for (int o = 32; o > 0; o >>= 1) v += __shfl_xor(v, o, 64);
  return v;
}

// bf16 helpers (storage-only compression of weights in LDS)
__device__ __forceinline__ float bfl(unsigned u) { return __uint_as_float(u << 16); }
__device__ __forceinline__ float bfh(unsigned u) { return __uint_as_float(u & 0xffff0000u); }
__device__ __forceinline__ unsigned short f2bf(float v) {
  unsigned u = __float_as_uint(v);
  return (unsigned short)((u + 0x7fff + ((u >> 16) & 1)) >> 16);  // RNE
}

// ---------------- CSR build ----------------
__global__ __launch_bounds__(256) void k_deg(const int* __restrict__ dst, int* deg) {
  int e = blockIdx.x * 256 + threadIdx.x;
  if (e < N_E) atomicAdd(&deg[dst[e]], 1);
}

__global__ __launch_bounds__(256) void k_bsum(const int* __restrict__ deg, int* __restrict__ bsum) {
  __shared__ int l[4];
  int t = threadIdx.x;
  int i = blockIdx.x * 256 + t;
  int v = (i < N_N) ? deg[i] : 0;
  int s = wsumi(v);
  if ((t & 63) == 0) l[t >> 6] = s;
  __syncthreads();
  if (t == 0) bsum[blockIdx.x] = l[0] + l[1] + l[2] + l[3];
}

__global__ __launch_bounds__(512) void k_scanb(const int* __restrict__ bsum, int* __restrict__ bofs, int nb) {
  __shared__ int l[512];
  int t = threadIdx.x;
  int v = (t < nb) ? bsum[t] : 0;
  l[t] = v;
  __syncthreads();
  for (int o = 1; o < 512; o <<= 1) {
    int a = (t >= o) ? l[t - o] : 0;
    __syncthreads();
    l[t] += a;
    __syncthreads();
  }
  if (t < nb) bofs[t] = l[t] - v;  // exclusive
}

__global__ __launch_bounds__(256) void k_indptr(const int* __restrict__ deg, const int* __restrict__ bofs,
                                                int* __restrict__ indptr) {
  __shared__ int l[256];
  int t = threadIdx.x;
  int i = blockIdx.x * 256 + t;
  int v = (i < N_N) ? deg[i] : 0;
  l[t] = v;
  __syncthreads();
  for (int o = 1; o < 256; o <<= 1) {
    int a = (t >= o) ? l[t - o] : 0;
    __syncthreads();
    l[t] += a;
    __syncthreads();
  }
  if (i < N_N) indptr[i] = bofs[blockIdx.x] + l[t] - v;
  if (i == 0) indptr[N_N] = N_E;
}

__global__ __launch_bounds__(256) void k_copyfill(const int* __restrict__ indptr, int* __restrict__ fill) {
  int i = blockIdx.x * 256 + threadIdx.x;
  if (i < N_N) fill[i] = indptr[i];
}

__global__ __launch_bounds__(256) void k_scatter(const int* __restrict__ src, const int* __restrict__ dst,
                                                 int* fill, int* __restrict__ csr) {
  int e = blockIdx.x * 256 + threadIdx.x;
  if (e < N_E) {
    int d = dst[e];
    int p = atomicAdd(&fill[d], 1);
    csr[p] = src[e];
  }
}

// deterministic order within each bucket (sum order fixed across runs)
__global__ __launch_bounds__(256) void k_sort(const int* __restrict__ indptr, int* __restrict__ csr) {
  int i = blockIdx.x * 256 + threadIdx.x;
  if (i >= N_N) return;
  int b = indptr[i], e = indptr[i + 1];
  for (int j = b + 1; j < e; ++j) {
    int key = csr[j];
    int k = j - 1;
    while (k >= b && csr[k] > key) { csr[k + 1] = csr[k]; --k; }
    csr[k + 1] = key;
  }
}

// ---------------- attention logits: al = x @ (W_h a_h) ----------------
template <int F>
__global__ __launch_bounds__(256) void k_avec(const float* __restrict__ W, const float* __restrict__ as_,
                                              const float* __restrict__ ad_, float* __restrict__ wsv,
                                              float* __restrict__ wdv) {
  int idx = blockIdx.x * 256 + threadIdx.x;
  if (idx >= HEADS * F) return;
  int h = idx / F, f = idx % F;
  float s = 0.f, d = 0.f;
  for (int c = 0; c < 64; ++c) {
    float w = W[(h * F + f) * 64 + c];
    s = fmaf(w, as_[h * 64 + c], s);
    d = fmaf(w, ad_[h * 64 + c], d);
  }
  wsv[idx] = s;
  wdv[idx] = d;
}

template <int F>
__global__ __launch_bounds__(256) void k_al(const float* __restrict__ xin, const float* __restrict__ wsv,
                                            const float* __restrict__ wdv, float* __restrict__ al_s,
                                            float* __restrict__ al_d) {
  int wv = threadIdx.x >> 6, lane = threadIdx.x & 63;
  for (int i = blockIdx.x * 4 + wv; i < N_N; i += gridDim.x * 4) {
    float xv = (lane < F) ? xin[(size_t)i * F + lane] : 0.f;
#pragma unroll
    for (int h = 0; h < HEADS; ++h) {
      float ws_ = (lane < F) ? wsv[h * F + lane] : 0.f;
      float wd_ = (lane < F) ? wdv[h * F + lane] : 0.f;
      float ss = wsum(xv * ws_);
      float sd = wsum(xv * wd_);
      if (lane == 0) {
        al_s[i * 4 + h] = ss;
        al_d[i * 4 + h] = sd;
      }
    }
  }
}

// ---------------- fused GAT layer ----------------
// wave per node, online softmax, unroll-16 gather, bf16-transposed-W epilogue.
// out[i,c] = relu( bias[c] + 0.25 * sum_h sum_f aggF[i,h,f] * W[h,f,c] )
template <int F, int NW>
__global__ __launch_bounds__(64 * NW, 5) void k_gat(const float* __restrict__ xin, const int* __restrict__ indptr,
                                                    const int* __restrict__ csr, const float* __restrict__ al_s,
                                                    const float* __restrict__ al_d, const float* __restrict__ W,
                                                    const float* __restrict__ bias, float* __restrict__ xg) {
  // row pad so lane-stride (WROW/2 dwords) has gcd(.,32)==2 -> 2-way LDS alias (free)
  constexpr int WROW = (F % 8 == 0) ? F + 4 : F + 8;  // 64->68, 28->36
  __shared__ unsigned short wlt[HEADS * 64 * WROW];   // W transposed [h][c][f], bf16
  __shared__ int s_idx[NW][64];
  __shared__ float4 s_w[NW][64];
  __shared__ float s_agg[NW][HEADS][F];
  int t = threadIdx.x;
  for (int idx = t; idx < HEADS * F * 64; idx += 64 * NW) {
    int c = idx & 63;
    int hf = idx >> 6;
    int f = hf % F;
    int h = hf / F;
    wlt[(h * 64 + c) * WROW + f] = f2bf(W[idx]);  // coalesced global read
  }
  __syncthreads();
  int wv = t >> 6, lane = t & 63;
  int lanef = lane & 31;  // used by dual-half (F=28) path
  int half = lane >> 5;
  for (int i = blockIdx.x * NW + wv; i < N_N; i += gridDim.x * NW) {
    int b = indptr[i], e = indptr[i + 1];
    float4 ad4 = *(const float4*)&al_d[i * 4];
    float4 as4 = *(const float4*)&al_s[i * 4];
    float es0 = lrelu(as4.x + ad4.x), es1 = lrelu(as4.y + ad4.y);
    float es2 = lrelu(as4.z + ad4.z), es3 = lrelu(as4.w + ad4.w);
    // running max per head (init = self-logit), accumulators, denominators
    float m0 = es0, m1 = es1, m2 = es2, m3 = es3;
    float xself = (lane < F) ? xin[(size_t)i * F + lane] : 0.f;
    float a0 = xself, a1 = xself, a2 = xself, a3 = xself;  // self weight exp(0)=1
    if (F == F_IN && half) { a0 = 0.f; a1 = 0.f; a2 = 0.f; a3 = 0.f; }
    float pd0 = 0.f, pd1 = 0.f, pd2 = 0.f, pd3 = 0.f;
    for (int cb = b; cb < e; cb += 64) {
      int cnt = min(64, e - cb);
      bool act = (cb + lane) < e;
      int s = 0;
      float e0 = -1e30f, e1 = -1e30f, e2 = -1e30f, e3 = -1e30f;
      if (act) {
        s = csr[cb + lane];
        float4 a4 = *(const float4*)&al_s[s * 4];
        e0 = lrelu(a4.x + ad4.x);
        e1 = lrelu(a4.y + ad4.y);
        e2 = lrelu(a4.z + ad4.z);
        e3 = lrelu(a4.w + ad4.w);
      }
      // online rescale to new running max
      float n0 = fmaxf(m0, wmax(e0)), n1 = fmaxf(m1, wmax(e1));
      float n2 = fmaxf(m2, wmax(e2)), n3 = fmaxf(m3, wmax(e3));
      float sc0 = __expf(m0 - n0), sc1 = __expf(m1 - n1);
      float sc2 = __expf(m2 - n2), sc3 = __expf(m3 - n3);
      a0 *= sc0; a1 *= sc1; a2 *= sc2; a3 *= sc3;
      pd0 *= sc0; pd1 *= sc1; pd2 *= sc2; pd3 *= sc3;
      m0 = n0; m1 = n1; m2 = n2; m3 = n3;
      // lane-parallel weights
      float w0 = act ? __expf(e0 - m0) : 0.f;
      float w1 = act ? __expf(e1 - m1) : 0.f;
      float w2 = act ? __expf(e2 - m2) : 0.f;
      float w3 = act ? __expf(e3 - m3) : 0.f;
      pd0 += w0; pd1 += w1; pd2 += w2; pd3 += w3;
      // stash indices + weights to wave-private LDS (inactive lanes: s=0, w=0)
      s_idx[wv][lane] = s;
      s_w[wv][lane] = make_float4(w0, w1, w2, w3);
      // (same-wave LDS RAW ordered by compiler-inserted lgkmcnt)
      if (F == F_IN) {
        // dual-edge: low half handles even edges, high half odd edges
        for (int je = 0; je < cnt; je += 32) {
          int sj[16];
#pragma unroll
          for (int u = 0; u < 16; ++u) sj[u] = s_idx[wv][je + 2 * u + half];
          float xr[16];
#pragma unroll
          for (int u = 0; u < 16; ++u)
            xr[u] = (lanef < F_IN) ? xin[(size_t)sj[u] * F_IN + lanef] : 0.f;
#pragma unroll
          for (int u = 0; u < 16; ++u) {
            float4 w4 = s_w[wv][je + 2 * u + half];
            a0 = fmaf(w4.x, xr[u], a0);
            a1 = fmaf(w4.y, xr[u], a1);
            a2 = fmaf(w4.z, xr[u], a2);
            a3 = fmaf(w4.w, xr[u], a3);
          }
        }
      } else {
        for (int je = 0; je < cnt; je += 16) {
          int sj[16];
#pragma unroll
          for (int u = 0; u < 16; ++u) sj[u] = s_idx[wv][je + u];
          float xr[16];
#pragma unroll
          for (int u = 0; u < 16; ++u) xr[u] = xin[(size_t)sj[u] * F + lane];
#pragma unroll
          for (int u = 0; u < 16; ++u) {
            float4 w4 = s_w[wv][je + u];
            a0 = fmaf(w4.x, xr[u], a0);
            a1 = fmaf(w4.y, xr[u], a1);
            a2 = fmaf(w4.z, xr[u], a2);
            a3 = fmaf(w4.w, xr[u], a3);
          }
        }
      }
    }
    if (F == F_IN) {
      // combine halves (lanes 0..27 and 32..59 get totals)
      a0 += __shfl_xor(a0, 32, 64);
      a1 += __shfl_xor(a1, 32, 64);
      a2 += __shfl_xor(a2, 32, 64);
      a3 += __shfl_xor(a3, 32, 64);
    }
    float dn0 = wsum(pd0) + __expf(es0 - m0);
    float dn1 = wsum(pd1) + __expf(es1 - m1);
    float dn2 = wsum(pd2) + __expf(es2 - m2);
    float dn3 = wsum(pd3) + __expf(es3 - m3);
    a0 /= dn0; a1 /= dn1; a2 /= dn2; a3 /= dn3;
    // stash normalized agg to LDS; GEMV via broadcast float4 + bf16 uint2 reads
    if (lane < F) {
      s_agg[wv][0][lane] = a0;
      s_agg[wv][1][lane] = a1;
      s_agg[wv][2][lane] = a2;
      s_agg[wv][3][lane] = a3;
    }
    float o0 = 0.f, o1 = 0.f, o2 = 0.f, o3 = 0.f;
    const unsigned short* w0r = &wlt[(0 * 64 + lane) * WROW];
    const unsigned short* w1r = &wlt[(1 * 64 + lane) * WROW];
    const unsigned short* w2r = &wlt[(2 * 64 + lane) * WROW];
    const unsigned short* w3r = &wlt[(3 * 64 + lane) * WROW];
#pragma unroll
    for (int f = 0; f < F; f += 4) {
      float4 g0 = *(const float4*)&s_agg[wv][0][f];
      float4 g1 = *(const float4*)&s_agg[wv][1][f];
      float4 g2 = *(const float4*)&s_agg[wv][2][f];
      float4 g3 = *(const float4*)&s_agg[wv][3][f];
      uint2 p0 = *(const uint2*)&w0r[f];
      uint2 p1 = *(const uint2*)&w1r[f];
      uint2 p2 = *(const uint2*)&w2r[f];
      uint2 p3 = *(const uint2*)&w3r[f];
      o0 = fmaf(bfl(p0.x), g0.x, o0); o0 = fmaf(bfh(p0.x), g0.y, o0);
      o0 = fmaf(bfl(p0.y), g0.z, o0); o0 = fmaf(bfh(p0.y), g0.w, o0);
      o1 = fmaf(bfl(p1.x), g1.x, o1); o1 = fmaf(bfh(p1.x), g1.y, o1);
      o1 = fmaf(bfl(p1.y), g1.z, o1); o1 = fmaf(bfh(p1.y), g1.w, o1);
      o2 = fmaf(bfl(p2.x), g2.x, o2); o2 = fmaf(bfh(p2.x), g2.y, o2);
      o2 = fmaf(bfl(p2.y), g2.z, o2); o2 = fmaf(bfh(p2.y), g2.w, o2);
      o3 = fmaf(bfl(p3.x), g3.x, o3); o3 = fmaf(bfh(p3.x), g3.y, o3);
      o3 = fmaf(bfl(p3.y), g3.z, o3); o3 = fmaf(bfh(p3.y), g3.w, o3);
    }
    float o = fmaxf(fmaf((o0 + o1) + (o2 + o3), 0.25f, bias[lane]), 0.f);
    xg[(size_t)i * 64 + lane] = o;
  }
}

// ---------------- fused GIN: agg + MLP + residual + LN (+ next-layer logits) --
template <int NW, bool FUSE_AL>
__global__ __launch_bounds__(64 * NW, 6) void k_gin(const int* __restrict__ indptr, const int* __restrict__ csr,
                                                    const float* __restrict__ xg, const float* __restrict__ w1,
                                                    const float* __restrict__ b1, const float* __restrict__ w2,
                                                    const float* __restrict__ b2, const float* __restrict__ lnw,
                                                    const float* __restrict__ lnb, float* __restrict__ xo,
                                                    const float* __restrict__ wsv, const float* __restrict__ wdv,
                                                    float* __restrict__ al_s, float* __restrict__ al_d) {
  __shared__ float w1l[4096], w2l[4096];
  int t = threadIdx.x;
  for (int idx = t; idx < 4096; idx += 64 * NW) {
    w1l[idx] = w1[idx];
    w2l[idx] = w2[idx];
  }
  __syncthreads();
  int wv = t >> 6, lane = t & 63;
  for (int i = blockIdx.x * NW + wv; i < N_N; i += gridDim.x * NW) {
    int b = indptr[i], e = indptr[i + 1];
    float xi = xg[(size_t)i * 64 + lane];
    float acc = xi;
    for (int j = b; j < e; j += 16) {
      int cj[16];
#pragma unroll
      for (int u = 0; u < 16; ++u) cj[u] = csr[min(j + u, e - 1)];
      float v[16];
#pragma unroll
      for (int u = 0; u < 16; ++u) v[u] = xg[(size_t)cj[u] * 64 + lane];
#pragma unroll
      for (int u = 0; u < 16; ++u) acc += (j + u) < e ? v[u] : 0.f;
    }
    float hv0 = b1[lane], hv1 = 0.f, hv2 = 0.f, hv3 = 0.f;
#pragma unroll
    for (int k = 0; k < 16; ++k) {
      hv0 = fmaf(__shfl(acc, k, 64), w1l[k * 64 + lane], hv0);
      hv1 = fmaf(__shfl(acc, k + 16, 64), w1l[(k + 16) * 64 + lane], hv1);
      hv2 = fmaf(__shfl(acc, k + 32, 64), w1l[(k + 32) * 64 + lane], hv2);
      hv3 = fmaf(__shfl(acc, k + 48, 64), w1l[(k + 48) * 64 + lane], hv3);
    }
    float hv = fmaxf((hv0 + hv1) + (hv2 + hv3), 0.f);
    float ov0 = b2[lane], ov1 = 0.f, ov2 = 0.f, ov3 = 0.f;
#pragma unroll
    for (int k = 0; k < 16; ++k) {
      ov0 = fmaf(__shfl(hv, k, 64), w2l[k * 64 + lane], ov0);
      ov1 = fmaf(__shfl(hv, k + 16, 64), w2l[(k + 16) * 64 + lane], ov1);
      ov2 = fmaf(__shfl(hv, k + 32, 64), w2l[(k + 32) * 64 + lane], ov2);
      ov3 = fmaf(__shfl(hv, k + 48, 64), w2l[(k + 48) * 64 + lane], ov3);
    }
    float res = xi + (ov0 + ov1) + (ov2 + ov3);
    float mu = wsum(res) * (1.f / 64.f);
    float d = res - mu;
    float var = wsum(d * d) * (1.f / 64.f);
    float xov = fmaf(d * rsqrtf(var + LN_EPS), lnw[lane], lnb[lane]);
    xo[(size_t)i * 64 + lane] = xov;
    if (FUSE_AL) {
#pragma unroll
      for (int h = 0; h < HEADS; ++h) {
        float ss = wsum(xov * wsv[h * 64 + lane]);
        float sd = wsum(xov * wdv[h * 64 + lane]);
        if (lane == 0) {
          al_s[i * 4 + h] = ss;
          al_d[i * 4 + h] = sd;
        }
      }
    }
  }
}

// ---------------- gate MLP ----------------
template <int NW>
__global__ __launch_bounds__(64 * NW, 4) void k_gatenn(const float* __restrict__ x2, const float* __restrict__ gw1,
                                                       const float* __restrict__ gb1, const float* __restrict__ gw2,
                                                       const float* __restrict__ gb2, float* __restrict__ gate) {
  __shared__ float wl[4096];
  __shared__ float g2l[64];
  int t = threadIdx.x;
  for (int idx = t; idx < 4096; idx += 64 * NW) wl[idx] = gw1[idx];
  if (t < 64) g2l[t] = gw2[t];
  __syncthreads();
  int wv = t >> 6, lane = t & 63;
  float gb2v = gb2[0];
  for (int i = blockIdx.x * NW + wv; i < N_N; i += gridDim.x * NW) {
    float vv = x2[(size_t)i * 64 + lane];
    float hv0 = gb1[lane], hv1 = 0.f, hv2 = 0.f, hv3 = 0.f;
#pragma unroll
    for (int k = 0; k < 16; ++k) {
      hv0 = fmaf(__shfl(vv, k, 64), wl[k * 64 + lane], hv0);
      hv1 = fmaf(__shfl(vv, k + 16, 64), wl[(k + 16) * 64 + lane], hv1);
      hv2 = fmaf(__shfl(vv, k + 32, 64), wl[(k + 32) * 64 + lane], hv2);
      hv3 = fmaf(__shfl(vv, k + 48, 64), wl[(k + 48) * 64 + lane], hv3);
    }
    float hv = fmaxf((hv0 + hv1) + (hv2 + hv3), 0.f);
    float g = wsum(hv * g2l[lane]);
    if (lane == 0) gate[i] = g + gb2v;
  }
}

// ---------------- graph ranges via counting ----------------
__global__ __launch_bounds__(256) void k_gcount(const int* __restrict__ batch, int* gcnt) {
  int i = blockIdx.x * 256 + threadIdx.x;
  if (i < N_N) atomicAdd(&gcnt[batch[i]], 1);
}

__global__ __launch_bounds__(256) void k_gptr(const int* __restrict__ gcnt, int* __restrict__ gptr) {
  __shared__ int l[256];
  int t = threadIdx.x;
  int v = gcnt[t];
  l[t] = v;
  __syncthreads();
  for (int o = 1; o < 256; o <<= 1) {
    int a = (t >= o) ? l[t - o] : 0;
    __syncthreads();
    l[t] += a;
    __syncthreads();
  }
  gptr[t] = l[t] - v;
  if (t == 255) gptr[256] = l[255];
}

// ---------------- global attention pool ----------------
__global__ __launch_bounds__(256) void k_pool(const int* __restrict__ gptr, const float* __restrict__ gate,
                                              const float* __restrict__ x2, float* __restrict__ pooled) {
  int g = blockIdx.x;
  int t = threadIdx.x, wv = t >> 6, lane = t & 63;
  __shared__ float red[256];
  int b = gptr[g], e = gptr[g + 1];
  if (b == e) {
    if (t < 64) pooled[g * 64 + t] = 0.f;
    return;
  }
  float m = -1e30f;
  for (int j = b + t; j < e; j += 256) m = fmaxf(m, gate[j]);
  m = wmax(m);
  if (lane == 0) red[wv] = m;
  __syncthreads();
  m = fmaxf(fmaxf(red[0], red[1]), fmaxf(red[2], red[3]));
  __syncthreads();
  float dn = 0.f;
  for (int j = b + t; j < e; j += 256) dn += __expf(gate[j] - m);
  dn = wsum(dn);
  if (lane == 0) red[wv] = dn;
  __syncthreads();
  dn = red[0] + red[1] + red[2] + red[3];
  __syncthreads();
  float acc = 0.f;
  for (int j = b + wv; j < e; j += 4) acc = fmaf(__expf(gate[j] - m), x2[(size_t)j * 64 + lane], acc);
  red[t] = acc;
  __syncthreads();
  if (t < 64) pooled[g * 64 + t] = (red[t] + red[t + 64] + red[t + 128] + red[t + 192]) / dn;
}

// ---------------- head MLP ----------------
__global__ __launch_bounds__(128) void k_head(const float* __restrict__ pooled, const float* __restrict__ l1w,
                                              const float* __restrict__ l1b, const float* __restrict__ lnfw,
                                              const float* __restrict__ lnfb, const float* __restrict__ l2w,
                                              const float* __restrict__ l2b, float* __restrict__ out) {
  int g = blockIdx.x, t = threadIdx.x;
  __shared__ float pl[64], zl[128], red[2];
  if (t < 64) pl[t] = pooled[g * 64 + t];
  __syncthreads();
  float y = l1b[t];
#pragma unroll 8
  for (int k = 0; k < 64; ++k) y = fmaf(pl[k], l1w[k * 128 + t], y);
  int wv = t >> 6, lane = t & 63;
  float s = wsum(y);
  if (lane == 0) red[wv] = s;
  __syncthreads();
  float mu = (red[0] + red[1]) * (1.f / 128.f);
  float d = y - mu;
  __syncthreads();
  s = wsum(d * d);
  if (lane == 0) red[wv] = s;
  __syncthreads();
  float var = (red[0] + red[1]) * (1.f / 128.f);
  float z = fmaxf(fmaf(d * rsqrtf(var + LN_EPS), lnfw[t], lnfb[t]), 0.f);
  zl[t] = z;
  __syncthreads();
  if (t < 6) {
    float o = l2b[t];
    for (int k = 0; k < 128; ++k) o = fmaf(zl[k], l2w[k * 6 + t], o);
    out[g * 6 + t] = o;
  }
}

extern "C" void kernel_launch(void* const* d_in, const int* in_sizes, int n_in,
                              void* d_out, int out_size, void* d_ws, size_t ws_size,
                              hipStream_t stream) {
  const float* x = (const float*)d_in[0];
  const int* src = (const int*)d_in[1];
  const int* dst = (const int*)d_in[2];
  const int* batch = (const int*)d_in[3];
  const float* W1 = (const float*)d_in[4];
  const float* a1s = (const float*)d_in[5];
  const float* a1d = (const float*)d_in[6];
  const float* bg1 = (const float*)d_in[7];
  const float* m1w1 = (const float*)d_in[8];
  const float* m1b1 = (const float*)d_in[9];
  const float* m1w2 = (const float*)d_in[10];
  const float* m1b2 = (const float*)d_in[11];
  const float* ln1w = (const float*)d_in[12];
  const float* ln1b = (const float*)d_in[13];
  const float* W2 = (const float*)d_in[14];
  const float* a2s = (const float*)d_in[15];
  const float* a2d = (const float*)d_in[16];
  const float* bg2 = (const float*)d_in[17];
  const float* m2w1 = (const float*)d_in[18];
  const float* m2b1 = (const float*)d_in[19];
  const float* m2w2 = (const float*)d_in[20];
  const float* m2b2 = (const float*)d_in[21];
  const float* ln2w = (const float*)d_in[22];
  const float* ln2b = (const float*)d_in[23];
  const float* gw1 = (const float*)d_in[24];
  const float* gb1 = (const float*)d_in[25];
  const float* gw2 = (const float*)d_in[26];
  const float* gb2 = (const float*)d_in[27];
  const float* l1w = (const float*)d_in[28];
  const float* l1b = (const float*)d_in[29];
  const float* lnfw = (const float*)d_in[30];
  const float* lnfb = (const float*)d_in[31];
  const float* l2w = (const float*)d_in[32];
  const float* l2b = (const float*)d_in[33];
  float* out = (float*)d_out;

  char* ws = (char*)d_ws;
  size_t off = 0;
  auto alloc = [&](size_t bytes) -> void* {
    void* p = ws + off;
    off += (bytes + 255) & ~(size_t)255;
    return p;
  };
  int* indptr = (int*)alloc((N_N + 1) * sizeof(int));
  int* fill = (int*)alloc(N_N * sizeof(int));       // also degree
  int* csr = (int*)alloc((size_t)N_E * sizeof(int));
  int* bsum = (int*)alloc(512 * sizeof(int));
  int* bofs = (int*)alloc(512 * sizeof(int));
  int* gcnt = (int*)alloc(257 * sizeof(int));
  int* gptr = (int*)alloc(257 * sizeof(int));
  float* wsv = (float*)alloc(HEADS * 64 * sizeof(float));
  float* wdv = (float*)alloc(HEADS * 64 * sizeof(float));
  float* al_s = (float*)alloc((size_t)N_N * 4 * sizeof(float));
  float* al_d = (float*)alloc((size_t)N_N * 4 * sizeof(float));
  float* gate = (float*)alloc((size_t)N_N * sizeof(float));
  float* pooled = (float*)alloc(N_G * 64 * sizeof(float));
  float* xg = (float*)alloc((size_t)N_N * 64 * sizeof(float));
  float* xv = (float*)alloc((size_t)N_N * 64 * sizeof(float));
  (void)ws_size; (void)n_in; (void)in_sizes; (void)out_size;

  const int NBE = (N_E + 255) / 256;
  const int NBN = (N_N + 255) / 256;  // 391

  hipMemsetAsync(fill, 0, (size_t)N_N * sizeof(int), stream);
  hipMemsetAsync(gcnt, 0, 257 * sizeof(int), stream);
  k_deg<<<NBE, 256, 0, stream>>>(dst, fill);
  k_bsum<<<NBN, 256, 0, stream>>>(fill, bsum);
  k_scanb<<<1, 512, 0, stream>>>(bsum, bofs, NBN);
  k_indptr<<<NBN, 256, 0, stream>>>(fill, bofs, indptr);
  k_copyfill<<<NBN, 256, 0, stream>>>(indptr, fill);
  k_scatter<<<NBE, 256, 0, stream>>>(src, dst, fill, csr);
  k_sort<<<NBN, 256, 0, stream>>>(indptr, csr);
  k_gcount<<<NBN, 256, 0, stream>>>(batch, gcnt);
  k_gptr<<<1, 256, 0, stream>>>(gcnt, gptr);

  // ---- layer 1 ----
  k_avec<F_IN><<<1, 256, 0, stream>>>(W1, a1s, a1d, wsv, wdv);
  k_al<F_IN><<<2048, 256, 0, stream>>>(x, wsv, wdv, al_s, al_d);
  k_gat<F_IN, 8><<<2048, 512, 0, stream>>>(x, indptr, csr, al_s, al_d, W1, bg1, xg);
  k_avec<CH><<<1, 256, 0, stream>>>(W2, a2s, a2d, wsv, wdv);  // layer-2 logit vectors
  k_gin<8, true><<<2048, 512, 0, stream>>>(indptr, csr, xg, m1w1, m1b1, m1w2, m1b2, ln1w, ln1b, xv,
                                           wsv, wdv, al_s, al_d);
  // ---- layer 2 ----
  k_gat<CH, 8><<<2048, 512, 0, stream>>>(xv, indptr, csr, al_s, al_d, W2, bg2, xg);
  k_gin<8, false><<<2048, 512, 0, stream>>>(indptr, csr, xg, m2w1, m2b1, m2w2, m2b2, ln2w, ln2b, xv,
                                            wsv, wdv, al_s, al_d);
  // ---- pooling + head ----
  k_gatenn<8><<<2048, 512, 0, stream>>>(xv, gw1, gb1, gw2, gb2, gate);
  k_pool<<<N_G, 256, 0, stream>>>(gptr, gate, xv, pooled);
  k_head<<<N_G, 128, 0, stream>>>(pooled, l1w, l1b, lnfw, lnfb, l2w, l2b, out);
}

// Round 5
// 3155.999 us; speedup vs baseline: 1.4817x; 1.4817x over previous
//
#include <hip/hip_runtime.h>

#define N_N 100000
#define N_E 1600000
#define N_G 256
#define F_IN 28
#define HEADS 4
#define CH 64
#define NEG 0.2f
#define LN_EPS 1e-5f

__device__ __forceinline__ float lrelu(float x) { return x > 0.f ? x : NEG * x; }

__device__ __forceinline__ float wsum(float v) {
#pragma unroll
  for (int o = 32; o > 0; o >>= 1) v += __shfl_xor(v, o, 64);
  return v;
}
__device__ __forceinline__ float wmax(float v) {
#pragma unroll
  for (int o = 32; o > 0; o >>= 1) v = fmaxf(v, __shfl_xor(v, o, 64));
  return v;
}
__device__ __forceinline__ int wsumi(int v) {
#pragma unroll
  for (int o = 32; o > 0; o >>= 1) v += __shfl_xor(v, o, 64);
  return v;
}

// bf16 helpers (storage-only compression of weights in LDS)
__device__ __forceinline__ float bfl(unsigned u) { return __uint_as_float(u << 16); }
__device__ __forceinline__ float bfh(unsigned u) { return __uint_as_float(u & 0xffff0000u); }
__device__ __forceinline__ unsigned short f2bf(float v) {
  unsigned u = __float_as_uint(v);
  return (unsigned short)((u + 0x7fff + ((u >> 16) & 1)) >> 16);  // RNE
}

// ---------------- CSR build ----------------
__global__ __launch_bounds__(256) void k_deg(const int* __restrict__ dst, int* deg) {
  int e = blockIdx.x * 256 + threadIdx.x;
  if (e < N_E) atomicAdd(&deg[dst[e]], 1);
}

__global__ __launch_bounds__(256) void k_bsum(const int* __restrict__ deg, int* __restrict__ bsum) {
  __shared__ int l[4];
  int t = threadIdx.x;
  int i = blockIdx.x * 256 + t;
  int v = (i < N_N) ? deg[i] : 0;
  int s = wsumi(v);
  if ((t & 63) == 0) l[t >> 6] = s;
  __syncthreads();
  if (t == 0) bsum[blockIdx.x] = l[0] + l[1] + l[2] + l[3];
}

__global__ __launch_bounds__(512) void k_scanb(const int* __restrict__ bsum, int* __restrict__ bofs, int nb) {
  __shared__ int l[512];
  int t = threadIdx.x;
  int v = (t < nb) ? bsum[t] : 0;
  l[t] = v;
  __syncthreads();
  for (int o = 1; o < 512; o <<= 1) {
    int a = (t >= o) ? l[t - o] : 0;
    __syncthreads();
    l[t] += a;
    __syncthreads();
  }
  if (t < nb) bofs[t] = l[t] - v;  // exclusive
}

__global__ __launch_bounds__(256) void k_indptr(const int* __restrict__ deg, const int* __restrict__ bofs,
                                                int* __restrict__ indptr) {
  __shared__ int l[256];
  int t = threadIdx.x;
  int i = blockIdx.x * 256 + t;
  int v = (i < N_N) ? deg[i] : 0;
  l[t] = v;
  __syncthreads();
  for (int o = 1; o < 256; o <<= 1) {
    int a = (t >= o) ? l[t - o] : 0;
    __syncthreads();
    l[t] += a;
    __syncthreads();
  }
  if (i < N_N) indptr[i] = bofs[blockIdx.x] + l[t] - v;
  if (i == 0) indptr[N_N] = N_E;
}

__global__ __launch_bounds__(256) void k_copyfill(const int* __restrict__ indptr, int* __restrict__ fill) {
  int i = blockIdx.x * 256 + threadIdx.x;
  if (i < N_N) fill[i] = indptr[i];
}

__global__ __launch_bounds__(256) void k_scatter(const int* __restrict__ src, const int* __restrict__ dst,
                                                 int* fill, int* __restrict__ csr) {
  int e = blockIdx.x * 256 + threadIdx.x;
  if (e < N_E) {
    int d = dst[e];
    int p = atomicAdd(&fill[d], 1);
    csr[p] = src[e];
  }
}

// deterministic order within each bucket (sum order fixed across runs)
__global__ __launch_bounds__(256) void k_sort(const int* __restrict__ indptr, int* __restrict__ csr) {
  int i = blockIdx.x * 256 + threadIdx.x;
  if (i >= N_N) return;
  int b = indptr[i], e = indptr[i + 1];
  for (int j = b + 1; j < e; ++j) {
    int key = csr[j];
    int k = j - 1;
    while (k >= b && csr[k] > key) { csr[k + 1] = csr[k]; --k; }
    csr[k + 1] = key;
  }
}

// ---------------- attention logits: al = x @ (W_h a_h) ----------------
template <int F>
__global__ __launch_bounds__(256) void k_avec(const float* __restrict__ W, const float* __restrict__ as_,
                                              const float* __restrict__ ad_, float* __restrict__ wsv,
                                              float* __restrict__ wdv) {
  int idx = blockIdx.x * 256 + threadIdx.x;
  if (idx >= HEADS * F) return;
  int h = idx / F, f = idx % F;
  float s = 0.f, d = 0.f;
  for (int c = 0; c < 64; ++c) {
    float w = W[(h * F + f) * 64 + c];
    s = fmaf(w, as_[h * 64 + c], s);
    d = fmaf(w, ad_[h * 64 + c], d);
  }
  wsv[idx] = s;
  wdv[idx] = d;
}

template <int F>
__global__ __launch_bounds__(256) void k_al(const float* __restrict__ xin, const float* __restrict__ wsv,
                                            const float* __restrict__ wdv, float* __restrict__ al_s,
                                            float* __restrict__ al_d) {
  int wv = threadIdx.x >> 6, lane = threadIdx.x & 63;
  for (int i = blockIdx.x * 4 + wv; i < N_N; i += gridDim.x * 4) {
    float xv = (lane < F) ? xin[(size_t)i * F + lane] : 0.f;
#pragma unroll
    for (int h = 0; h < HEADS; ++h) {
      float ws_ = (lane < F) ? wsv[h * F + lane] : 0.f;
      float wd_ = (lane < F) ? wdv[h * F + lane] : 0.f;
      float ss = wsum(xv * ws_);
      float sd = wsum(xv * wd_);
      if (lane == 0) {
        al_s[i * 4 + h] = ss;
        al_d[i * 4 + h] = sd;
      }
    }
  }
}

// ---------------- fused GAT layer ----------------
// wave per node, online softmax, unroll-8 gather, bf16-transposed-W epilogue.
// out[i,c] = relu( bias[c] + 0.25 * sum_h sum_f aggF[i,h,f] * W[h,f,c] )
template <int F, int NW>
__global__ __launch_bounds__(64 * NW, 4) void k_gat(const float* __restrict__ xin, const int* __restrict__ indptr,
                                                    const int* __restrict__ csr, const float* __restrict__ al_s,
                                                    const float* __restrict__ al_d, const float* __restrict__ W,
                                                    const float* __restrict__ bias, float* __restrict__ xg) {
  // WROW = F+2 shorts: row stride F/2+1 dwords (odd) -> conflict-free lane pattern
  constexpr int WROW = F + 2;                        // 64->66, 28->30
  __shared__ unsigned short wlt[HEADS * 64 * WROW];  // W transposed [h][c][f], bf16
  __shared__ int s_idx[NW][64];
  __shared__ float4 s_w[NW][64];
  __shared__ float s_agg[NW][HEADS][F];
  int t = threadIdx.x;
  for (int idx = t; idx < HEADS * F * 64; idx += 64 * NW) {
    int c = idx & 63;
    int hf = idx >> 6;
    int f = hf % F;
    int h = hf / F;
    wlt[(h * 64 + c) * WROW + f] = f2bf(W[idx]);  // coalesced global read
  }
  __syncthreads();
  int wv = t >> 6, lane = t & 63;
  int lanef = lane & 31;  // used by dual-half (F=28) path
  int half = lane >> 5;
  for (int i = blockIdx.x * NW + wv; i < N_N; i += gridDim.x * NW) {
    int b = indptr[i], e = indptr[i + 1];
    float4 ad4 = *(const float4*)&al_d[i * 4];
    float4 as4 = *(const float4*)&al_s[i * 4];
    float es0 = lrelu(as4.x + ad4.x), es1 = lrelu(as4.y + ad4.y);
    float es2 = lrelu(as4.z + ad4.z), es3 = lrelu(as4.w + ad4.w);
    // running max per head (init = self-logit), accumulators, denominators
    float m0 = es0, m1 = es1, m2 = es2, m3 = es3;
    float xself = (lane < F) ? xin[(size_t)i * F + lane] : 0.f;
    float a0 = xself, a1 = xself, a2 = xself, a3 = xself;  // self weight exp(0)=1
    if (F == F_IN && half) { a0 = 0.f; a1 = 0.f; a2 = 0.f; a3 = 0.f; }
    float pd0 = 0.f, pd1 = 0.f, pd2 = 0.f, pd3 = 0.f;
    for (int cb = b; cb < e; cb += 64) {
      int cnt = min(64, e - cb);
      bool act = (cb + lane) < e;
      int s = 0;
      float e0 = -1e30f, e1 = -1e30f, e2 = -1e30f, e3 = -1e30f;
      if (act) {
        s = csr[cb + lane];
        float4 a4 = *(const float4*)&al_s[s * 4];
        e0 = lrelu(a4.x + ad4.x);
        e1 = lrelu(a4.y + ad4.y);
        e2 = lrelu(a4.z + ad4.z);
        e3 = lrelu(a4.w + ad4.w);
      }
      // online rescale to new running max
      float n0 = fmaxf(m0, wmax(e0)), n1 = fmaxf(m1, wmax(e1));
      float n2 = fmaxf(m2, wmax(e2)), n3 = fmaxf(m3, wmax(e3));
      float sc0 = __expf(m0 - n0), sc1 = __expf(m1 - n1);
      float sc2 = __expf(m2 - n2), sc3 = __expf(m3 - n3);
      a0 *= sc0; a1 *= sc1; a2 *= sc2; a3 *= sc3;
      pd0 *= sc0; pd1 *= sc1; pd2 *= sc2; pd3 *= sc3;
      m0 = n0; m1 = n1; m2 = n2; m3 = n3;
      // lane-parallel weights
      float w0 = act ? __expf(e0 - m0) : 0.f;
      float w1 = act ? __expf(e1 - m1) : 0.f;
      float w2 = act ? __expf(e2 - m2) : 0.f;
      float w3 = act ? __expf(e3 - m3) : 0.f;
      pd0 += w0; pd1 += w1; pd2 += w2; pd3 += w3;
      // stash indices + weights to wave-private LDS (inactive lanes: s=0, w=0)
      s_idx[wv][lane] = s;
      s_w[wv][lane] = make_float4(w0, w1, w2, w3);
      // (same-wave LDS RAW ordered by compiler-inserted lgkmcnt)
      if (F == F_IN) {
        // dual-edge: low half handles even edges, high half odd edges
        for (int je = 0; je < cnt; je += 16) {
          int sj[8];
#pragma unroll
          for (int u = 0; u < 8; ++u) sj[u] = s_idx[wv][je + 2 * u + half];
          float xr[8];
#pragma unroll
          for (int u = 0; u < 8; ++u)
            xr[u] = (lanef < F_IN) ? xin[(size_t)sj[u] * F_IN + lanef] : 0.f;
#pragma unroll
          for (int u = 0; u < 8; ++u) {
            float4 w4 = s_w[wv][je + 2 * u + half];
            a0 = fmaf(w4.x, xr[u], a0);
            a1 = fmaf(w4.y, xr[u], a1);
            a2 = fmaf(w4.z, xr[u], a2);
            a3 = fmaf(w4.w, xr[u], a3);
          }
        }
      } else {
        for (int je = 0; je < cnt; je += 8) {
          int sj[8];
#pragma unroll
          for (int u = 0; u < 8; ++u) sj[u] = s_idx[wv][je + u];
          float xr[8];
#pragma unroll
          for (int u = 0; u < 8; ++u) xr[u] = xin[(size_t)sj[u] * F + lane];
#pragma unroll
          for (int u = 0; u < 8; ++u) {
            float4 w4 = s_w[wv][je + u];
            a0 = fmaf(w4.x, xr[u], a0);
            a1 = fmaf(w4.y, xr[u], a1);
            a2 = fmaf(w4.z, xr[u], a2);
            a3 = fmaf(w4.w, xr[u], a3);
          }
        }
      }
    }
    if (F == F_IN) {
      // combine halves (lanes 0..27 and 32..59 get totals)
      a0 += __shfl_xor(a0, 32, 64);
      a1 += __shfl_xor(a1, 32, 64);
      a2 += __shfl_xor(a2, 32, 64);
      a3 += __shfl_xor(a3, 32, 64);
    }
    float dn0 = wsum(pd0) + __expf(es0 - m0);
    float dn1 = wsum(pd1) + __expf(es1 - m1);
    float dn2 = wsum(pd2) + __expf(es2 - m2);
    float dn3 = wsum(pd3) + __expf(es3 - m3);
    a0 /= dn0; a1 /= dn1; a2 /= dn2; a3 /= dn3;
    // stash normalized agg to LDS; GEMV via broadcast float4 + bf16 dword reads
    if (lane < F) {
      s_agg[wv][0][lane] = a0;
      s_agg[wv][1][lane] = a1;
      s_agg[wv][2][lane] = a2;
      s_agg[wv][3][lane] = a3;
    }
    float o0 = 0.f, o1 = 0.f, o2 = 0.f, o3 = 0.f;
    const unsigned* w0r = (const unsigned*)&wlt[(0 * 64 + lane) * WROW];
    const unsigned* w1r = (const unsigned*)&wlt[(1 * 64 + lane) * WROW];
    const unsigned* w2r = (const unsigned*)&wlt[(2 * 64 + lane) * WROW];
    const unsigned* w3r = (const unsigned*)&wlt[(3 * 64 + lane) * WROW];
#pragma unroll
    for (int f = 0; f < F; f += 4) {
      float4 g0 = *(const float4*)&s_agg[wv][0][f];
      float4 g1 = *(const float4*)&s_agg[wv][1][f];
      float4 g2 = *(const float4*)&s_agg[wv][2][f];
      float4 g3 = *(const float4*)&s_agg[wv][3][f];
      unsigned q0a = w0r[f / 2], q0b = w0r[f / 2 + 1];
      unsigned q1a = w1r[f / 2], q1b = w1r[f / 2 + 1];
      unsigned q2a = w2r[f / 2], q2b = w2r[f / 2 + 1];
      unsigned q3a = w3r[f / 2], q3b = w3r[f / 2 + 1];
      o0 = fmaf(bfl(q0a), g0.x, o0); o0 = fmaf(bfh(q0a), g0.y, o0);
      o0 = fmaf(bfl(q0b), g0.z, o0); o0 = fmaf(bfh(q0b), g0.w, o0);
      o1 = fmaf(bfl(q1a), g1.x, o1); o1 = fmaf(bfh(q1a), g1.y, o1);
      o1 = fmaf(bfl(q1b), g1.z, o1); o1 = fmaf(bfh(q1b), g1.w, o1);
      o2 = fmaf(bfl(q2a), g2.x, o2); o2 = fmaf(bfh(q2a), g2.y, o2);
      o2 = fmaf(bfl(q2b), g2.z, o2); o2 = fmaf(bfh(q2b), g2.w, o2);
      o3 = fmaf(bfl(q3a), g3.x, o3); o3 = fmaf(bfh(q3a), g3.y, o3);
      o3 = fmaf(bfl(q3b), g3.z, o3); o3 = fmaf(bfh(q3b), g3.w, o3);
    }
    float o = fmaxf(fmaf((o0 + o1) + (o2 + o3), 0.25f, bias[lane]), 0.f);
    xg[(size_t)i * 64 + lane] = o;
  }
}

// ---------------- fused GIN: agg + MLP + residual + LN (+ next-layer logits) --
template <int NW, bool FUSE_AL>
__global__ __launch_bounds__(64 * NW, 4) void k_gin(const int* __restrict__ indptr, const int* __restrict__ csr,
                                                    const float* __restrict__ xg, const float* __restrict__ w1,
                                                    const float* __restrict__ b1, const float* __restrict__ w2,
                                                    const float* __restrict__ b2, const float* __restrict__ lnw,
                                                    const float* __restrict__ lnb, float* __restrict__ xo,
                                                    const float* __restrict__ wsv, const float* __restrict__ wdv,
                                                    float* __restrict__ al_s, float* __restrict__ al_d) {
  __shared__ float w1l[4096], w2l[4096];
  int t = threadIdx.x;
  for (int idx = t; idx < 4096; idx += 64 * NW) {
    w1l[idx] = w1[idx];
    w2l[idx] = w2[idx];
  }
  __syncthreads();
  int wv = t >> 6, lane = t & 63;
  for (int i = blockIdx.x * NW + wv; i < N_N; i += gridDim.x * NW) {
    int b = indptr[i], e = indptr[i + 1];
    float xi = xg[(size_t)i * 64 + lane];
    float acc = xi;
    for (int j = b; j < e; j += 8) {
      int cj[8];
#pragma unroll
      for (int u = 0; u < 8; ++u) cj[u] = csr[min(j + u, e - 1)];
      float v[8];
#pragma unroll
      for (int u = 0; u < 8; ++u) v[u] = xg[(size_t)cj[u] * 64 + lane];
#pragma unroll
      for (int u = 0; u < 8; ++u) acc += (j + u) < e ? v[u] : 0.f;
    }
    float hv0 = b1[lane], hv1 = 0.f, hv2 = 0.f, hv3 = 0.f;
#pragma unroll
    for (int k = 0; k < 16; ++k) {
      hv0 = fmaf(__shfl(acc, k, 64), w1l[k * 64 + lane], hv0);
      hv1 = fmaf(__shfl(acc, k + 16, 64), w1l[(k + 16) * 64 + lane], hv1);
      hv2 = fmaf(__shfl(acc, k + 32, 64), w1l[(k + 32) * 64 + lane], hv2);
      hv3 = fmaf(__shfl(acc, k + 48, 64), w1l[(k + 48) * 64 + lane], hv3);
    }
    float hv = fmaxf((hv0 + hv1) + (hv2 + hv3), 0.f);
    float ov0 = b2[lane], ov1 = 0.f, ov2 = 0.f, ov3 = 0.f;
#pragma unroll
    for (int k = 0; k < 16; ++k) {
      ov0 = fmaf(__shfl(hv, k, 64), w2l[k * 64 + lane], ov0);
      ov1 = fmaf(__shfl(hv, k + 16, 64), w2l[(k + 16) * 64 + lane], ov1);
      ov2 = fmaf(__shfl(hv, k + 32, 64), w2l[(k + 32) * 64 + lane], ov2);
      ov3 = fmaf(__shfl(hv, k + 48, 64), w2l[(k + 48) * 64 + lane], ov3);
    }
    float res = xi + (ov0 + ov1) + (ov2 + ov3);
    float mu = wsum(res) * (1.f / 64.f);
    float d = res - mu;
    float var = wsum(d * d) * (1.f / 64.f);
    float xov = fmaf(d * rsqrtf(var + LN_EPS), lnw[lane], lnb[lane]);
    xo[(size_t)i * 64 + lane] = xov;
    if (FUSE_AL) {
#pragma unroll
      for (int h = 0; h < HEADS; ++h) {
        float ss = wsum(xov * wsv[h * 64 + lane]);
        float sd = wsum(xov * wdv[h * 64 + lane]);
        if (lane == 0) {
          al_s[i * 4 + h] = ss;
          al_d[i * 4 + h] = sd;
        }
      }
    }
  }
}

// ---------------- gate MLP ----------------
template <int NW>
__global__ __launch_bounds__(64 * NW, 4) void k_gatenn(const float* __restrict__ x2, const float* __restrict__ gw1,
                                                       const float* __restrict__ gb1, const float* __restrict__ gw2,
                                                       const float* __restrict__ gb2, float* __restrict__ gate) {
  __shared__ float wl[4096];
  __shared__ float g2l[64];
  int t = threadIdx.x;
  for (int idx = t; idx < 4096; idx += 64 * NW) wl[idx] = gw1[idx];
  if (t < 64) g2l[t] = gw2[t];
  __syncthreads();
  int wv = t >> 6, lane = t & 63;
  float gb2v = gb2[0];
  for (int i = blockIdx.x * NW + wv; i < N_N; i += gridDim.x * NW) {
    float vv = x2[(size_t)i * 64 + lane];
    float hv0 = gb1[lane], hv1 = 0.f, hv2 = 0.f, hv3 = 0.f;
#pragma unroll
    for (int k = 0; k < 16; ++k) {
      hv0 = fmaf(__shfl(vv, k, 64), wl[k * 64 + lane], hv0);
      hv1 = fmaf(__shfl(vv, k + 16, 64), wl[(k + 16) * 64 + lane], hv1);
      hv2 = fmaf(__shfl(vv, k + 32, 64), wl[(k + 32) * 64 + lane], hv2);
      hv3 = fmaf(__shfl(vv, k + 48, 64), wl[(k + 48) * 64 + lane], hv3);
    }
    float hv = fmaxf((hv0 + hv1) + (hv2 + hv3), 0.f);
    float g = wsum(hv * g2l[lane]);
    if (lane == 0) gate[i] = g + gb2v;
  }
}

// ---------------- graph ranges via counting ----------------
__global__ __launch_bounds__(256) void k_gcount(const int* __restrict__ batch, int* gcnt) {
  int i = blockIdx.x * 256 + threadIdx.x;
  if (i < N_N) atomicAdd(&gcnt[batch[i]], 1);
}

__global__ __launch_bounds__(256) void k_gptr(const int* __restrict__ gcnt, int* __restrict__ gptr) {
  __shared__ int l[256];
  int t = threadIdx.x;
  int v = gcnt[t];
  l[t] = v;
  __syncthreads();
  for (int o = 1; o < 256; o <<= 1) {
    int a = (t >= o) ? l[t - o] : 0;
    __syncthreads();
    l[t] += a;
    __syncthreads();
  }
  gptr[t] = l[t] - v;
  if (t == 255) gptr[256] = l[255];
}

// ---------------- global attention pool ----------------
__global__ __launch_bounds__(256) void k_pool(const int* __restrict__ gptr, const float* __restrict__ gate,
                                              const float* __restrict__ x2, float* __restrict__ pooled) {
  int g = blockIdx.x;
  int t = threadIdx.x, wv = t >> 6, lane = t & 63;
  __shared__ float red[256];
  int b = gptr[g], e = gptr[g + 1];
  if (b == e) {
    if (t < 64) pooled[g * 64 + t] = 0.f;
    return;
  }
  float m = -1e30f;
  for (int j = b + t; j < e; j += 256) m = fmaxf(m, gate[j]);
  m = wmax(m);
  if (lane == 0) red[wv] = m;
  __syncthreads();
  m = fmaxf(fmaxf(red[0], red[1]), fmaxf(red[2], red[3]));
  __syncthreads();
  float dn = 0.f;
  for (int j = b + t; j < e; j += 256) dn += __expf(gate[j] - m);
  dn = wsum(dn);
  if (lane == 0) red[wv] = dn;
  __syncthreads();
  dn = red[0] + red[1] + red[2] + red[3];
  __syncthreads();
  float acc = 0.f;
  for (int j = b + wv; j < e; j += 4) acc = fmaf(__expf(gate[j] - m), x2[(size_t)j * 64 + lane], acc);
  red[t] = acc;
  __syncthreads();
  if (t < 64) pooled[g * 64 + t] = (red[t] + red[t + 64] + red[t + 128] + red[t + 192]) / dn;
}

// ---------------- head MLP ----------------
__global__ __launch_bounds__(128) void k_head(const float* __restrict__ pooled, const float* __restrict__ l1w,
                                              const float* __restrict__ l1b, const float* __restrict__ lnfw,
                                              const float* __restrict__ lnfb, const float* __restrict__ l2w,
                                              const float* __restrict__ l2b, float* __restrict__ out) {
  int g = blockIdx.x, t = threadIdx.x;
  __shared__ float pl[64], zl[128], red[2];
  if (t < 64) pl[t] = pooled[g * 64 + t];
  __syncthreads();
  float y = l1b[t];
#pragma unroll 8
  for (int k = 0; k < 64; ++k) y = fmaf(pl[k], l1w[k * 128 + t], y);
  int wv = t >> 6, lane = t & 63;
  float s = wsum(y);
  if (lane == 0) red[wv] = s;
  __syncthreads();
  float mu = (red[0] + red[1]) * (1.f / 128.f);
  float d = y - mu;
  __syncthreads();
  s = wsum(d * d);
  if (lane == 0) red[wv] = s;
  __syncthreads();
  float var = (red[0] + red[1]) * (1.f / 128.f);
  float z = fmaxf(fmaf(d * rsqrtf(var + LN_EPS), lnfw[t], lnfb[t]), 0.f);
  zl[t] = z;
  __syncthreads();
  if (t < 6) {
    float o = l2b[t];
    for (int k = 0; k < 128; ++k) o = fmaf(zl[k], l2w[k * 6 + t], o);
    out[g * 6 + t] = o;
  }
}

extern "C" void kernel_launch(void* const* d_in, const int* in_sizes, int n_in,
                              void* d_out, int out_size, void* d_ws, size_t ws_size,
                              hipStream_t stream) {
  const float* x = (const float*)d_in[0];
  const int* src = (const int*)d_in[1];
  const int* dst = (const int*)d_in[2];
  const int* batch = (const int*)d_in[3];
  const float* W1 = (const float*)d_in[4];
  const float* a1s = (const float*)d_in[5];
  const float* a1d = (const float*)d_in[6];
  const float* bg1 = (const float*)d_in[7];
  const float* m1w1 = (const float*)d_in[8];
  const float* m1b1 = (const float*)d_in[9];
  const float* m1w2 = (const float*)d_in[10];
  const float* m1b2 = (const float*)d_in[11];
  const float* ln1w = (const float*)d_in[12];
  const float* ln1b = (const float*)d_in[13];
  const float* W2 = (const float*)d_in[14];
  const float* a2s = (const float*)d_in[15];
  const float* a2d = (const float*)d_in[16];
  const float* bg2 = (const float*)d_in[17];
  const float* m2w1 = (const float*)d_in[18];
  const float* m2b1 = (const float*)d_in[19];
  const float* m2w2 = (const float*)d_in[20];
  const float* m2b2 = (const float*)d_in[21];
  const float* ln2w = (const float*)d_in[22];
  const float* ln2b = (const float*)d_in[23];
  const float* gw1 = (const float*)d_in[24];
  const float* gb1 = (const float*)d_in[25];
  const float* gw2 = (const float*)d_in[26];
  const float* gb2 = (const float*)d_in[27];
  const float* l1w = (const float*)d_in[28];
  const float* l1b = (const float*)d_in[29];
  const float* lnfw = (const float*)d_in[30];
  const float* lnfb = (const float*)d_in[31];
  const float* l2w = (const float*)d_in[32];
  const float* l2b = (const float*)d_in[33];
  float* out = (float*)d_out;

  char* ws = (char*)d_ws;
  size_t off = 0;
  auto alloc = [&](size_t bytes) -> void* {
    void* p = ws + off;
    off += (bytes + 255) & ~(size_t)255;
    return p;
  };
  int* indptr = (int*)alloc((N_N + 1) * sizeof(int));
  int* fill = (int*)alloc(N_N * sizeof(int));       // also degree
  int* csr = (int*)alloc((size_t)N_E * sizeof(int));
  int* bsum = (int*)alloc(512 * sizeof(int));
  int* bofs = (int*)alloc(512 * sizeof(int));
  int* gcnt = (int*)alloc(257 * sizeof(int));
  int* gptr = (int*)alloc(257 * sizeof(int));
  float* wsv = (float*)alloc(HEADS * 64 * sizeof(float));
  float* wdv = (float*)alloc(HEADS * 64 * sizeof(float));
  float* al_s = (float*)alloc((size_t)N_N * 4 * sizeof(float));
  float* al_d = (float*)alloc((size_t)N_N * 4 * sizeof(float));
  float* gate = (float*)alloc((size_t)N_N * sizeof(float));
  float* pooled = (float*)alloc(N_G * 64 * sizeof(float));
  float* xg = (float*)alloc((size_t)N_N * 64 * sizeof(float));
  float* xv = (float*)alloc((size_t)N_N * 64 * sizeof(float));
  (void)ws_size; (void)n_in; (void)in_sizes; (void)out_size;

  const int NBE = (N_E + 255) / 256;
  const int NBN = (N_N + 255) / 256;  // 391

  hipMemsetAsync(fill, 0, (size_t)N_N * sizeof(int), stream);
  hipMemsetAsync(gcnt, 0, 257 * sizeof(int), stream);
  k_deg<<<NBE, 256, 0, stream>>>(dst, fill);
  k_bsum<<<NBN, 256, 0, stream>>>(fill, bsum);
  k_scanb<<<1, 512, 0, stream>>>(bsum, bofs, NBN);
  k_indptr<<<NBN, 256, 0, stream>>>(fill, bofs, indptr);
  k_copyfill<<<NBN, 256, 0, stream>>>(indptr, fill);
  k_scatter<<<NBE, 256, 0, stream>>>(src, dst, fill, csr);
  k_sort<<<NBN, 256, 0, stream>>>(indptr, csr);
  k_gcount<<<NBN, 256, 0, stream>>>(batch, gcnt);
  k_gptr<<<1, 256, 0, stream>>>(gcnt, gptr);

  // ---- layer 1 ----
  k_avec<F_IN><<<1, 256, 0, stream>>>(W1, a1s, a1d, wsv, wdv);
  k_al<F_IN><<<2048, 256, 0, stream>>>(x, wsv, wdv, al_s, al_d);
  k_gat<F_IN, 8><<<2048, 512, 0, stream>>>(x, indptr, csr, al_s, al_d, W1, bg1, xg);
  k_avec<CH><<<1, 256, 0, stream>>>(W2, a2s, a2d, wsv, wdv);  // layer-2 logit vectors
  k_gin<8, true><<<2048, 512, 0, stream>>>(indptr, csr, xg, m1w1, m1b1, m1w2, m1b2, ln1w, ln1b, xv,
                                           wsv, wdv, al_s, al_d);
  // ---- layer 2 ----
  k_gat<CH, 8><<<2048, 512, 0, stream>>>(xv, indptr, csr, al_s, al_d, W2, bg2, xg);
  k_gin<8, false><<<2048, 512, 0, stream>>>(indptr, csr, xg, m2w1, m2b1, m2w2, m2b2, ln2w, ln2b, xv,
                                            wsv, wdv, al_s, al_d);
  // ---- pooling + head ----
  k_gatenn<8><<<2048, 512, 0, stream>>>(xv, gw1, gb1, gw2, gb2, gate);
  k_pool<<<N_G, 256, 0, stream>>>(gptr, gate, xv, pooled);
  k_head<<<N_G, 128, 0, stream>>>(pooled, l1w, l1b, lnfw, lnfb, l2w, l2b, out);
}

// Round 6
// 1782.489 us; speedup vs baseline: 2.6234x; 1.7706x over previous
//
#include <hip/hip_runtime.h>

#define N_N 100000
#define N_E 1600000
#define N_G 256
#define F_IN 28
#define HEADS 4
#define CH 64
#define NEG 0.2f
#define LN_EPS 1e-5f

__device__ __forceinline__ float lrelu(float x) { return x > 0.f ? x : NEG * x; }

__device__ __forceinline__ float wsum(float v) {
#pragma unroll
  for (int o = 32; o > 0; o >>= 1) v += __shfl_xor(v, o, 64);
  return v;
}
__device__ __forceinline__ float wmax(float v) {
#pragma unroll
  for (int o = 32; o > 0; o >>= 1) v = fmaxf(v, __shfl_xor(v, o, 64));
  return v;
}
__device__ __forceinline__ int wsumi(int v) {
#pragma unroll
  for (int o = 32; o > 0; o >>= 1) v += __shfl_xor(v, o, 64);
  return v;
}

// bf16 helpers (storage-only compression of weights in LDS)
__device__ __forceinline__ float bfs(unsigned short u) {
  return __uint_as_float((unsigned)u << 16);
}
__device__ __forceinline__ unsigned short f2bf(float v) {
  unsigned u = __float_as_uint(v);
  return (unsigned short)((u + 0x7fff + ((u >> 16) & 1)) >> 16);  // RNE
}

// ---------------- CSR build ----------------
__global__ __launch_bounds__(256) void k_deg(const int* __restrict__ dst, int* deg) {
  int e = blockIdx.x * 256 + threadIdx.x;
  if (e < N_E) atomicAdd(&deg[dst[e]], 1);
}

__global__ __launch_bounds__(256) void k_bsum(const int* __restrict__ deg, int* __restrict__ bsum) {
  __shared__ int l[4];
  int t = threadIdx.x;
  int i = blockIdx.x * 256 + t;
  int v = (i < N_N) ? deg[i] : 0;
  int s = wsumi(v);
  if ((t & 63) == 0) l[t >> 6] = s;
  __syncthreads();
  if (t == 0) bsum[blockIdx.x] = l[0] + l[1] + l[2] + l[3];
}

__global__ __launch_bounds__(512) void k_scanb(const int* __restrict__ bsum, int* __restrict__ bofs, int nb) {
  __shared__ int l[512];
  int t = threadIdx.x;
  int v = (t < nb) ? bsum[t] : 0;
  l[t] = v;
  __syncthreads();
  for (int o = 1; o < 512; o <<= 1) {
    int a = (t >= o) ? l[t - o] : 0;
    __syncthreads();
    l[t] += a;
    __syncthreads();
  }
  if (t < nb) bofs[t] = l[t] - v;  // exclusive
}

__global__ __launch_bounds__(256) void k_indptr(const int* __restrict__ deg, const int* __restrict__ bofs,
                                                int* __restrict__ indptr) {
  __shared__ int l[256];
  int t = threadIdx.x;
  int i = blockIdx.x * 256 + t;
  int v = (i < N_N) ? deg[i] : 0;
  l[t] = v;
  __syncthreads();
  for (int o = 1; o < 256; o <<= 1) {
    int a = (t >= o) ? l[t - o] : 0;
    __syncthreads();
    l[t] += a;
    __syncthreads();
  }
  if (i < N_N) indptr[i] = bofs[blockIdx.x] + l[t] - v;
  if (i == 0) indptr[N_N] = N_E;
}

__global__ __launch_bounds__(256) void k_copyfill(const int* __restrict__ indptr, int* __restrict__ fill) {
  int i = blockIdx.x * 256 + threadIdx.x;
  if (i < N_N) fill[i] = indptr[i];
}

__global__ __launch_bounds__(256) void k_scatter(const int* __restrict__ src, const int* __restrict__ dst,
                                                 int* fill, int* __restrict__ csr) {
  int e = blockIdx.x * 256 + threadIdx.x;
  if (e < N_E) {
    int d = dst[e];
    int p = atomicAdd(&fill[d], 1);
    csr[p] = src[e];
  }
}

// deterministic order within each bucket (sum order fixed across runs)
__global__ __launch_bounds__(256) void k_sort(const int* __restrict__ indptr, int* __restrict__ csr) {
  int i = blockIdx.x * 256 + threadIdx.x;
  if (i >= N_N) return;
  int b = indptr[i], e = indptr[i + 1];
  for (int j = b + 1; j < e; ++j) {
    int key = csr[j];
    int k = j - 1;
    while (k >= b && csr[k] > key) { csr[k + 1] = csr[k]; --k; }
    csr[k + 1] = key;
  }
}

// ---------------- attention logits: al = x @ (W_h a_h) ----------------
template <int F>
__global__ __launch_bounds__(256) void k_avec(const float* __restrict__ W, const float* __restrict__ as_,
                                              const float* __restrict__ ad_, float* __restrict__ wsv,
                                              float* __restrict__ wdv) {
  int idx = blockIdx.x * 256 + threadIdx.x;
  if (idx >= HEADS * F) return;
  int h = idx / F, f = idx % F;
  float s = 0.f, d = 0.f;
  for (int c = 0; c < 64; ++c) {
    float w = W[(h * F + f) * 64 + c];
    s = fmaf(w, as_[h * 64 + c], s);
    d = fmaf(w, ad_[h * 64 + c], d);
  }
  wsv[idx] = s;
  wdv[idx] = d;
}

template <int F>
__global__ __launch_bounds__(256) void k_al(const float* __restrict__ xin, const float* __restrict__ wsv,
                                            const float* __restrict__ wdv, float* __restrict__ al_s,
                                            float* __restrict__ al_d) {
  int wv = threadIdx.x >> 6, lane = threadIdx.x & 63;
  for (int i = blockIdx.x * 4 + wv; i < N_N; i += gridDim.x * 4) {
    float xv = (lane < F) ? xin[(size_t)i * F + lane] : 0.f;
#pragma unroll
    for (int h = 0; h < HEADS; ++h) {
      float ws_ = (lane < F) ? wsv[h * F + lane] : 0.f;
      float wd_ = (lane < F) ? wdv[h * F + lane] : 0.f;
      float ss = wsum(xv * ws_);
      float sd = wsum(xv * wd_);
      if (lane == 0) {
        al_s[i * 4 + h] = ss;
        al_d[i * 4 + h] = sd;
      }
    }
  }
}

// ---------------- fused GAT layer ----------------
// wave per node, online softmax, unroll-8 gather, bf16 W in LDS, shfl epilogue.
// out[i,c] = relu( bias[c] + 0.25 * sum_h sum_f aggF[i,h,f] * W[h,f,c] )
template <int F, int NW>
__global__ __launch_bounds__(64 * NW, 4) void k_gat(const float* __restrict__ xin, const int* __restrict__ indptr,
                                                    const int* __restrict__ csr, const float* __restrict__ al_s,
                                                    const float* __restrict__ al_d, const float* __restrict__ W,
                                                    const float* __restrict__ bias, float* __restrict__ xg) {
  __shared__ unsigned short wl[HEADS * F * 64];  // bf16, same [h][f][c] layout
  __shared__ int s_idx[NW][64];
  __shared__ float4 s_w[NW][64];
  int t = threadIdx.x;
  for (int idx = t; idx < HEADS * F * 64; idx += 64 * NW) wl[idx] = f2bf(W[idx]);
  __syncthreads();
  int wv = t >> 6, lane = t & 63;
  int lanef = lane & 31;  // used by dual-half (F=28) path
  int half = lane >> 5;
  for (int i = blockIdx.x * NW + wv; i < N_N; i += gridDim.x * NW) {
    int b = indptr[i], e = indptr[i + 1];
    float4 ad4 = *(const float4*)&al_d[i * 4];
    float4 as4 = *(const float4*)&al_s[i * 4];
    float es0 = lrelu(as4.x + ad4.x), es1 = lrelu(as4.y + ad4.y);
    float es2 = lrelu(as4.z + ad4.z), es3 = lrelu(as4.w + ad4.w);
    // running max per head (init = self-logit), accumulators, denominators
    float m0 = es0, m1 = es1, m2 = es2, m3 = es3;
    float xself = (lane < F) ? xin[(size_t)i * F + lane] : 0.f;
    float a0 = xself, a1 = xself, a2 = xself, a3 = xself;  // self weight exp(0)=1
    if (F == F_IN && half) { a0 = 0.f; a1 = 0.f; a2 = 0.f; a3 = 0.f; }
    float pd0 = 0.f, pd1 = 0.f, pd2 = 0.f, pd3 = 0.f;
    for (int cb = b; cb < e; cb += 64) {
      int cnt = min(64, e - cb);
      bool act = (cb + lane) < e;
      int s = 0;
      float e0 = -1e30f, e1 = -1e30f, e2 = -1e30f, e3 = -1e30f;
      if (act) {
        s = csr[cb + lane];
        float4 a4 = *(const float4*)&al_s[s * 4];
        e0 = lrelu(a4.x + ad4.x);
        e1 = lrelu(a4.y + ad4.y);
        e2 = lrelu(a4.z + ad4.z);
        e3 = lrelu(a4.w + ad4.w);
      }
      // online rescale to new running max
      float n0 = fmaxf(m0, wmax(e0)), n1 = fmaxf(m1, wmax(e1));
      float n2 = fmaxf(m2, wmax(e2)), n3 = fmaxf(m3, wmax(e3));
      float sc0 = __expf(m0 - n0), sc1 = __expf(m1 - n1);
      float sc2 = __expf(m2 - n2), sc3 = __expf(m3 - n3);
      a0 *= sc0; a1 *= sc1; a2 *= sc2; a3 *= sc3;
      pd0 *= sc0; pd1 *= sc1; pd2 *= sc2; pd3 *= sc3;
      m0 = n0; m1 = n1; m2 = n2; m3 = n3;
      // lane-parallel weights
      float w0 = act ? __expf(e0 - m0) : 0.f;
      float w1 = act ? __expf(e1 - m1) : 0.f;
      float w2 = act ? __expf(e2 - m2) : 0.f;
      float w3 = act ? __expf(e3 - m3) : 0.f;
      pd0 += w0; pd1 += w1; pd2 += w2; pd3 += w3;
      // stash indices + weights to wave-private LDS (inactive lanes: s=0, w=0)
      s_idx[wv][lane] = s;
      s_w[wv][lane] = make_float4(w0, w1, w2, w3);
      // (same-wave LDS RAW ordered by compiler-inserted lgkmcnt)
      if (F == F_IN) {
        // dual-edge: low half handles even edges, high half odd edges
        for (int je = 0; je < cnt; je += 16) {
          int sj[8];
#pragma unroll
          for (int u = 0; u < 8; ++u) sj[u] = s_idx[wv][je + 2 * u + half];
          float xr[8];
#pragma unroll
          for (int u = 0; u < 8; ++u)
            xr[u] = (lanef < F_IN) ? xin[(size_t)sj[u] * F_IN + lanef] : 0.f;
#pragma unroll
          for (int u = 0; u < 8; ++u) {
            float4 w4 = s_w[wv][je + 2 * u + half];
            a0 = fmaf(w4.x, xr[u], a0);
            a1 = fmaf(w4.y, xr[u], a1);
            a2 = fmaf(w4.z, xr[u], a2);
            a3 = fmaf(w4.w, xr[u], a3);
          }
        }
      } else {
        for (int je = 0; je < cnt; je += 8) {
          int sj[8];
#pragma unroll
          for (int u = 0; u < 8; ++u) sj[u] = s_idx[wv][je + u];
          float xr[8];
#pragma unroll
          for (int u = 0; u < 8; ++u) xr[u] = xin[(size_t)sj[u] * F + lane];
#pragma unroll
          for (int u = 0; u < 8; ++u) {
            float4 w4 = s_w[wv][je + u];
            a0 = fmaf(w4.x, xr[u], a0);
            a1 = fmaf(w4.y, xr[u], a1);
            a2 = fmaf(w4.z, xr[u], a2);
            a3 = fmaf(w4.w, xr[u], a3);
          }
        }
      }
    }
    if (F == F_IN) {
      // combine halves (lanes 0..27 and 32..59 get totals)
      a0 += __shfl_xor(a0, 32, 64);
      a1 += __shfl_xor(a1, 32, 64);
      a2 += __shfl_xor(a2, 32, 64);
      a3 += __shfl_xor(a3, 32, 64);
    }
    float dn0 = wsum(pd0) + __expf(es0 - m0);
    float dn1 = wsum(pd1) + __expf(es1 - m1);
    float dn2 = wsum(pd2) + __expf(es2 - m2);
    float dn3 = wsum(pd3) + __expf(es3 - m3);
    a0 /= dn0; a1 /= dn1; a2 /= dn2; a3 /= dn3;
    // apply W: per-head accumulators, shfl broadcast + bf16 LDS read
    float o0 = 0.f, o1 = 0.f, o2 = 0.f, o3 = 0.f;
#pragma unroll 4
    for (int f = 0; f < F; ++f) {
      float v0 = __shfl(a0, f, 64);
      float v1 = __shfl(a1, f, 64);
      float v2 = __shfl(a2, f, 64);
      float v3 = __shfl(a3, f, 64);
      o0 = fmaf(v0, bfs(wl[(0 * F + f) * 64 + lane]), o0);
      o1 = fmaf(v1, bfs(wl[(1 * F + f) * 64 + lane]), o1);
      o2 = fmaf(v2, bfs(wl[(2 * F + f) * 64 + lane]), o2);
      o3 = fmaf(v3, bfs(wl[(3 * F + f) * 64 + lane]), o3);
    }
    float o = fmaxf(fmaf((o0 + o1) + (o2 + o3), 0.25f, bias[lane]), 0.f);
    xg[(size_t)i * 64 + lane] = o;
  }
}

// ---- fused GIN: agg + MLP + residual + LN (+ next-layer logits / gate) ----
template <int NW, bool FUSE_AL, bool FUSE_GATE>
__global__ __launch_bounds__(64 * NW, 4) void k_gin(const int* __restrict__ indptr, const int* __restrict__ csr,
                                                    const float* __restrict__ xg, const float* __restrict__ w1,
                                                    const float* __restrict__ b1, const float* __restrict__ w2,
                                                    const float* __restrict__ b2, const float* __restrict__ lnw,
                                                    const float* __restrict__ lnb, float* __restrict__ xo,
                                                    const float* __restrict__ wsv, const float* __restrict__ wdv,
                                                    float* __restrict__ al_s, float* __restrict__ al_d,
                                                    const float* __restrict__ gw1, const float* __restrict__ gb1,
                                                    const float* __restrict__ gw2, const float* __restrict__ gb2,
                                                    float* __restrict__ gate) {
  __shared__ float w1l[4096], w2l[4096];
  __shared__ unsigned short gw1l[FUSE_GATE ? 4096 : 64];
  int t = threadIdx.x;
  for (int idx = t; idx < 4096; idx += 64 * NW) {
    w1l[idx] = w1[idx];
    w2l[idx] = w2[idx];
  }
  if (FUSE_GATE) {
    for (int idx = t; idx < 4096; idx += 64 * NW) gw1l[idx] = f2bf(gw1[idx]);
  }
  __syncthreads();
  int wv = t >> 6, lane = t & 63;
  float gb1v = FUSE_GATE ? gb1[lane] : 0.f;
  float g2v = FUSE_GATE ? gw2[lane] : 0.f;
  float gb2v = FUSE_GATE ? gb2[0] : 0.f;
  for (int i = blockIdx.x * NW + wv; i < N_N; i += gridDim.x * NW) {
    int b = indptr[i], e = indptr[i + 1];
    float xi = xg[(size_t)i * 64 + lane];
    float acc = xi;
    for (int j = b; j < e; j += 8) {
      int cj[8];
#pragma unroll
      for (int u = 0; u < 8; ++u) cj[u] = csr[min(j + u, e - 1)];
      float v[8];
#pragma unroll
      for (int u = 0; u < 8; ++u) v[u] = xg[(size_t)cj[u] * 64 + lane];
#pragma unroll
      for (int u = 0; u < 8; ++u) acc += (j + u) < e ? v[u] : 0.f;
    }
    float hv0 = b1[lane], hv1 = 0.f, hv2 = 0.f, hv3 = 0.f;
#pragma unroll 4
    for (int k = 0; k < 16; ++k) {
      hv0 = fmaf(__shfl(acc, k, 64), w1l[k * 64 + lane], hv0);
      hv1 = fmaf(__shfl(acc, k + 16, 64), w1l[(k + 16) * 64 + lane], hv1);
      hv2 = fmaf(__shfl(acc, k + 32, 64), w1l[(k + 32) * 64 + lane], hv2);
      hv3 = fmaf(__shfl(acc, k + 48, 64), w1l[(k + 48) * 64 + lane], hv3);
    }
    float hv = fmaxf((hv0 + hv1) + (hv2 + hv3), 0.f);
    float ov0 = b2[lane], ov1 = 0.f, ov2 = 0.f, ov3 = 0.f;
#pragma unroll 4
    for (int k = 0; k < 16; ++k) {
      ov0 = fmaf(__shfl(hv, k, 64), w2l[k * 64 + lane], ov0);
      ov1 = fmaf(__shfl(hv, k + 16, 64), w2l[(k + 16) * 64 + lane], ov1);
      ov2 = fmaf(__shfl(hv, k + 32, 64), w2l[(k + 32) * 64 + lane], ov2);
      ov3 = fmaf(__shfl(hv, k + 48, 64), w2l[(k + 48) * 64 + lane], ov3);
    }
    float res = xi + (ov0 + ov1) + (ov2 + ov3);
    float mu = wsum(res) * (1.f / 64.f);
    float d = res - mu;
    float var = wsum(d * d) * (1.f / 64.f);
    float xov = fmaf(d * rsqrtf(var + LN_EPS), lnw[lane], lnb[lane]);
    xo[(size_t)i * 64 + lane] = xov;
    if (FUSE_AL) {
#pragma unroll
      for (int h = 0; h < HEADS; ++h) {
        float ss = wsum(xov * wsv[h * 64 + lane]);
        float sd = wsum(xov * wdv[h * 64 + lane]);
        if (lane == 0) {
          al_s[i * 4 + h] = ss;
          al_d[i * 4 + h] = sd;
        }
      }
    }
    if (FUSE_GATE) {
      float hg0 = gb1v, hg1 = 0.f, hg2 = 0.f, hg3 = 0.f;
#pragma unroll 4
      for (int k = 0; k < 16; ++k) {
        hg0 = fmaf(__shfl(xov, k, 64), bfs(gw1l[k * 64 + lane]), hg0);
        hg1 = fmaf(__shfl(xov, k + 16, 64), bfs(gw1l[(k + 16) * 64 + lane]), hg1);
        hg2 = fmaf(__shfl(xov, k + 32, 64), bfs(gw1l[(k + 32) * 64 + lane]), hg2);
        hg3 = fmaf(__shfl(xov, k + 48, 64), bfs(gw1l[(k + 48) * 64 + lane]), hg3);
      }
      float hg = fmaxf((hg0 + hg1) + (hg2 + hg3), 0.f);
      float g = wsum(hg * g2v);
      if (lane == 0) gate[i] = g + gb2v;
    }
  }
}

// ---------------- graph ranges via counting ----------------
__global__ __launch_bounds__(256) void k_gcount(const int* __restrict__ batch, int* gcnt) {
  int i = blockIdx.x * 256 + threadIdx.x;
  if (i < N_N) atomicAdd(&gcnt[batch[i]], 1);
}

__global__ __launch_bounds__(256) void k_gptr(const int* __restrict__ gcnt, int* __restrict__ gptr) {
  __shared__ int l[256];
  int t = threadIdx.x;
  int v = gcnt[t];
  l[t] = v;
  __syncthreads();
  for (int o = 1; o < 256; o <<= 1) {
    int a = (t >= o) ? l[t - o] : 0;
    __syncthreads();
    l[t] += a;
    __syncthreads();
  }
  gptr[t] = l[t] - v;
  if (t == 255) gptr[256] = l[255];
}

// ---------------- global attention pool ----------------
__global__ __launch_bounds__(256) void k_pool(const int* __restrict__ gptr, const float* __restrict__ gate,
                                              const float* __restrict__ x2, float* __restrict__ pooled) {
  int g = blockIdx.x;
  int t = threadIdx.x, wv = t >> 6, lane = t & 63;
  __shared__ float red[256];
  int b = gptr[g], e = gptr[g + 1];
  if (b == e) {
    if (t < 64) pooled[g * 64 + t] = 0.f;
    return;
  }
  float m = -1e30f;
  for (int j = b + t; j < e; j += 256) m = fmaxf(m, gate[j]);
  m = wmax(m);
  if (lane == 0) red[wv] = m;
  __syncthreads();
  m = fmaxf(fmaxf(red[0], red[1]), fmaxf(red[2], red[3]));
  __syncthreads();
  float dn = 0.f;
  for (int j = b + t; j < e; j += 256) dn += __expf(gate[j] - m);
  dn = wsum(dn);
  if (lane == 0) red[wv] = dn;
  __syncthreads();
  dn = red[0] + red[1] + red[2] + red[3];
  __syncthreads();
  float acc = 0.f;
  for (int j = b + wv; j < e; j += 4) acc = fmaf(__expf(gate[j] - m), x2[(size_t)j * 64 + lane], acc);
  red[t] = acc;
  __syncthreads();
  if (t < 64) pooled[g * 64 + t] = (red[t] + red[t + 64] + red[t + 128] + red[t + 192]) / dn;
}

// ---------------- head MLP ----------------
__global__ __launch_bounds__(128) void k_head(const float* __restrict__ pooled, const float* __restrict__ l1w,
                                              const float* __restrict__ l1b, const float* __restrict__ lnfw,
                                              const float* __restrict__ lnfb, const float* __restrict__ l2w,
                                              const float* __restrict__ l2b, float* __restrict__ out) {
  int g = blockIdx.x, t = threadIdx.x;
  __shared__ float pl[64], zl[128], red[2];
  if (t < 64) pl[t] = pooled[g * 64 + t];
  __syncthreads();
  float y = l1b[t];
#pragma unroll 8
  for (int k = 0; k < 64; ++k) y = fmaf(pl[k], l1w[k * 128 + t], y);
  int wv = t >> 6, lane = t & 63;
  float s = wsum(y);
  if (lane == 0) red[wv] = s;
  __syncthreads();
  float mu = (red[0] + red[1]) * (1.f / 128.f);
  float d = y - mu;
  __syncthreads();
  s = wsum(d * d);
  if (lane == 0) red[wv] = s;
  __syncthreads();
  float var = (red[0] + red[1]) * (1.f / 128.f);
  float z = fmaxf(fmaf(d * rsqrtf(var + LN_EPS), lnfw[t], lnfb[t]), 0.f);
  zl[t] = z;
  __syncthreads();
  if (t < 6) {
    float o = l2b[t];
    for (int k = 0; k < 128; ++k) o = fmaf(zl[k], l2w[k * 6 + t], o);
    out[g * 6 + t] = o;
  }
}

extern "C" void kernel_launch(void* const* d_in, const int* in_sizes, int n_in,
                              void* d_out, int out_size, void* d_ws, size_t ws_size,
                              hipStream_t stream) {
  const float* x = (const float*)d_in[0];
  const int* src = (const int*)d_in[1];
  const int* dst = (const int*)d_in[2];
  const int* batch = (const int*)d_in[3];
  const float* W1 = (const float*)d_in[4];
  const float* a1s = (const float*)d_in[5];
  const float* a1d = (const float*)d_in[6];
  const float* bg1 = (const float*)d_in[7];
  const float* m1w1 = (const float*)d_in[8];
  const float* m1b1 = (const float*)d_in[9];
  const float* m1w2 = (const float*)d_in[10];
  const float* m1b2 = (const float*)d_in[11];
  const float* ln1w = (const float*)d_in[12];
  const float* ln1b = (const float*)d_in[13];
  const float* W2 = (const float*)d_in[14];
  const float* a2s = (const float*)d_in[15];
  const float* a2d = (const float*)d_in[16];
  const float* bg2 = (const float*)d_in[17];
  const float* m2w1 = (const float*)d_in[18];
  const float* m2b1 = (const float*)d_in[19];
  const float* m2w2 = (const float*)d_in[20];
  const float* m2b2 = (const float*)d_in[21];
  const float* ln2w = (const float*)d_in[22];
  const float* ln2b = (const float*)d_in[23];
  const float* gw1 = (const float*)d_in[24];
  const float* gb1 = (const float*)d_in[25];
  const float* gw2 = (const float*)d_in[26];
  const float* gb2 = (const float*)d_in[27];
  const float* l1w = (const float*)d_in[28];
  const float* l1b = (const float*)d_in[29];
  const float* lnfw = (const float*)d_in[30];
  const float* lnfb = (const float*)d_in[31];
  const float* l2w = (const float*)d_in[32];
  const float* l2b = (const float*)d_in[33];
  float* out = (float*)d_out;

  char* ws = (char*)d_ws;
  size_t off = 0;
  auto alloc = [&](size_t bytes) -> void* {
    void* p = ws + off;
    off += (bytes + 255) & ~(size_t)255;
    return p;
  };
  int* indptr = (int*)alloc((N_N + 1) * sizeof(int));
  int* fill = (int*)alloc(N_N * sizeof(int));       // also degree
  int* csr = (int*)alloc((size_t)N_E * sizeof(int));
  int* bsum = (int*)alloc(512 * sizeof(int));
  int* bofs = (int*)alloc(512 * sizeof(int));
  int* gcnt = (int*)alloc(257 * sizeof(int));
  int* gptr = (int*)alloc(257 * sizeof(int));
  float* wsv = (float*)alloc(HEADS * 64 * sizeof(float));
  float* wdv = (float*)alloc(HEADS * 64 * sizeof(float));
  float* al_s = (float*)alloc((size_t)N_N * 4 * sizeof(float));
  float* al_d = (float*)alloc((size_t)N_N * 4 * sizeof(float));
  float* gate = (float*)alloc((size_t)N_N * sizeof(float));
  float* pooled = (float*)alloc(N_G * 64 * sizeof(float));
  float* xg = (float*)alloc((size_t)N_N * 64 * sizeof(float));
  float* xv = (float*)alloc((size_t)N_N * 64 * sizeof(float));
  (void)ws_size; (void)n_in; (void)in_sizes; (void)out_size;

  const int NBE = (N_E + 255) / 256;
  const int NBN = (N_N + 255) / 256;  // 391

  hipMemsetAsync(fill, 0, (size_t)N_N * sizeof(int), stream);
  hipMemsetAsync(gcnt, 0, 257 * sizeof(int), stream);
  k_deg<<<NBE, 256, 0, stream>>>(dst, fill);
  k_bsum<<<NBN, 256, 0, stream>>>(fill, bsum);
  k_scanb<<<1, 512, 0, stream>>>(bsum, bofs, NBN);
  k_indptr<<<NBN, 256, 0, stream>>>(fill, bofs, indptr);
  k_copyfill<<<NBN, 256, 0, stream>>>(indptr, fill);
  k_scatter<<<NBE, 256, 0, stream>>>(src, dst, fill, csr);
  k_sort<<<NBN, 256, 0, stream>>>(indptr, csr);
  k_gcount<<<NBN, 256, 0, stream>>>(batch, gcnt);
  k_gptr<<<1, 256, 0, stream>>>(gcnt, gptr);

  // ---- layer 1 ----
  k_avec<F_IN><<<1, 256, 0, stream>>>(W1, a1s, a1d, wsv, wdv);
  k_al<F_IN><<<2048, 256, 0, stream>>>(x, wsv, wdv, al_s, al_d);
  k_gat<F_IN, 8><<<2048, 512, 0, stream>>>(x, indptr, csr, al_s, al_d, W1, bg1, xg);
  k_avec<CH><<<1, 256, 0, stream>>>(W2, a2s, a2d, wsv, wdv);  // layer-2 logit vectors
  k_gin<8, true, false><<<2048, 512, 0, stream>>>(indptr, csr, xg, m1w1, m1b1, m1w2, m1b2, ln1w, ln1b,
                                                  xv, wsv, wdv, al_s, al_d, gw1, gb1, gw2, gb2, gate);
  // ---- layer 2 ----
  k_gat<CH, 8><<<2048, 512, 0, stream>>>(xv, indptr, csr, al_s, al_d, W2, bg2, xg);
  k_gin<8, false, true><<<2048, 512, 0, stream>>>(indptr, csr, xg, m2w1, m2b1, m2w2, m2b2, ln2w, ln2b,
                                                  xv, wsv, wdv, al_s, al_d, gw1, gb1, gw2, gb2, gate);
  // ---- pooling + head ----
  k_pool<<<N_G, 256, 0, stream>>>(gptr, gate, xv, pooled);
  k_head<<<N_G, 128, 0, stream>>>(pooled, l1w, l1b, lnfw, lnfb, l2w, l2b, out);
}

// Round 7
// 1058.663 us; speedup vs baseline: 4.4171x; 1.6837x over previous
//
#include <hip/hip_runtime.h>

#define N_N 100000
#define N_E 1600000
#define N_G 256
#define F_IN 28
#define HEADS 4
#define CH 64
#define NEG 0.2f
#define LN_EPS 1e-5f

typedef __attribute__((ext_vector_type(8))) short short8v;   // 8 bf16
typedef __attribute__((ext_vector_type(4))) float float4v;   // MFMA acc

__device__ __forceinline__ float lrelu(float x) { return x > 0.f ? x : NEG * x; }

__device__ __forceinline__ float wsum(float v) {
#pragma unroll
  for (int o = 32; o > 0; o >>= 1) v += __shfl_xor(v, o, 64);
  return v;
}
__device__ __forceinline__ float wmax(float v) {
#pragma unroll
  for (int o = 32; o > 0; o >>= 1) v = fmaxf(v, __shfl_xor(v, o, 64));
  return v;
}
__device__ __forceinline__ int wsumi(int v) {
#pragma unroll
  for (int o = 32; o > 0; o >>= 1) v += __shfl_xor(v, o, 64);
  return v;
}

// bf16 helpers (storage-only compression in LDS)
__device__ __forceinline__ float bfs(unsigned short u) {
  return __uint_as_float((unsigned)u << 16);
}
__device__ __forceinline__ unsigned short f2bf(float v) {
  unsigned u = __float_as_uint(v);
  return (unsigned short)((u + 0x7fff + ((u >> 16) & 1)) >> 16);  // RNE
}

// ---------------- CSR build ----------------
__global__ __launch_bounds__(256) void k_deg(const int* __restrict__ dst, int* deg) {
  int e = blockIdx.x * 256 + threadIdx.x;
  if (e < N_E) atomicAdd(&deg[dst[e]], 1);
}

__global__ __launch_bounds__(256) void k_bsum(const int* __restrict__ deg, int* __restrict__ bsum) {
  __shared__ int l[4];
  int t = threadIdx.x;
  int i = blockIdx.x * 256 + t;
  int v = (i < N_N) ? deg[i] : 0;
  int s = wsumi(v);
  if ((t & 63) == 0) l[t >> 6] = s;
  __syncthreads();
  if (t == 0) bsum[blockIdx.x] = l[0] + l[1] + l[2] + l[3];
}

__global__ __launch_bounds__(512) void k_scanb(const int* __restrict__ bsum, int* __restrict__ bofs, int nb) {
  __shared__ int l[512];
  int t = threadIdx.x;
  int v = (t < nb) ? bsum[t] : 0;
  l[t] = v;
  __syncthreads();
  for (int o = 1; o < 512; o <<= 1) {
    int a = (t >= o) ? l[t - o] : 0;
    __syncthreads();
    l[t] += a;
    __syncthreads();
  }
  if (t < nb) bofs[t] = l[t] - v;  // exclusive
}

__global__ __launch_bounds__(256) void k_indptr(const int* __restrict__ deg, const int* __restrict__ bofs,
                                                int* __restrict__ indptr) {
  __shared__ int l[256];
  int t = threadIdx.x;
  int i = blockIdx.x * 256 + t;
  int v = (i < N_N) ? deg[i] : 0;
  l[t] = v;
  __syncthreads();
  for (int o = 1; o < 256; o <<= 1) {
    int a = (t >= o) ? l[t - o] : 0;
    __syncthreads();
    l[t] += a;
    __syncthreads();
  }
  if (i < N_N) indptr[i] = bofs[blockIdx.x] + l[t] - v;
  if (i == 0) indptr[N_N] = N_E;
}

__global__ __launch_bounds__(256) void k_copyfill(const int* __restrict__ indptr, int* __restrict__ fill) {
  int i = blockIdx.x * 256 + threadIdx.x;
  if (i < N_N) fill[i] = indptr[i];
}

__global__ __launch_bounds__(256) void k_scatter(const int* __restrict__ src, const int* __restrict__ dst,
                                                 int* fill, int* __restrict__ csr) {
  int e = blockIdx.x * 256 + threadIdx.x;
  if (e < N_E) {
    int d = dst[e];
    int p = atomicAdd(&fill[d], 1);
    csr[p] = src[e];
  }
}

// deterministic order within each bucket (sum order fixed across runs)
__global__ __launch_bounds__(256) void k_sort(const int* __restrict__ indptr, int* __restrict__ csr) {
  int i = blockIdx.x * 256 + threadIdx.x;
  if (i >= N_N) return;
  int b = indptr[i], e = indptr[i + 1];
  for (int j = b + 1; j < e; ++j) {
    int key = csr[j];
    int k = j - 1;
    while (k >= b && csr[k] > key) { csr[k + 1] = csr[k]; --k; }
    csr[k + 1] = key;
  }
}

// ---------------- attention logits: al = x @ (W_h a_h) ----------------
template <int F>
__global__ __launch_bounds__(256) void k_avec(const float* __restrict__ W, const float* __restrict__ as_,
                                              const float* __restrict__ ad_, float* __restrict__ wsv,
                                              float* __restrict__ wdv) {
  int idx = blockIdx.x * 256 + threadIdx.x;
  if (idx >= HEADS * F) return;
  int h = idx / F, f = idx % F;
  float s = 0.f, d = 0.f;
  for (int c = 0; c < 64; ++c) {
    float w = W[(h * F + f) * 64 + c];
    s = fmaf(w, as_[h * 64 + c], s);
    d = fmaf(w, ad_[h * 64 + c], d);
  }
  wsv[idx] = s;
  wdv[idx] = d;
}

template <int F>
__global__ __launch_bounds__(256) void k_al(const float* __restrict__ xin, const float* __restrict__ wsv,
                                            const float* __restrict__ wdv, float* __restrict__ al_s,
                                            float* __restrict__ al_d) {
  int wv = threadIdx.x >> 6, lane = threadIdx.x & 63;
  for (int i = blockIdx.x * 4 + wv; i < N_N; i += gridDim.x * 4) {
    float xv = (lane < F) ? xin[(size_t)i * F + lane] : 0.f;
#pragma unroll
    for (int h = 0; h < HEADS; ++h) {
      float ws_ = (lane < F) ? wsv[h * F + lane] : 0.f;
      float wd_ = (lane < F) ? wdv[h * F + lane] : 0.f;
      float ss = wsum(xv * ws_);
      float sd = wsum(xv * wd_);
      if (lane == 0) {
        al_s[i * 4 + h] = ss;
        al_d[i * 4 + h] = sd;
      }
    }
  }
}

// ---------------- fused GAT layer ----------------
// 16 nodes per block iteration: 8 waves aggregate 2 nodes each (online softmax,
// unroll-8 gather), stage agg to LDS (bf16), then 4 waves apply W via MFMA.
// out[i,c] = relu( bias[c] + 0.25 * sum_h sum_f aggF[i,h,f] * W[h,f,c] )
template <int F, int NW>
__global__ __launch_bounds__(64 * NW, 4) void k_gat(const float* __restrict__ xin, const int* __restrict__ indptr,
                                                    const int* __restrict__ csr, const float* __restrict__ al_s,
                                                    const float* __restrict__ al_d, const float* __restrict__ W,
                                                    const float* __restrict__ bias, float* __restrict__ xg) {
  constexpr int K = HEADS * F;        // 256 / 112
  constexpr int KP = (K + 31) & ~31;  // MFMA K coverage: 256 / 128
  constexpr int KROW = KP + 8;        // 16B-aligned rows, bank-staggered
  __shared__ unsigned short Bt[64][KROW];   // W^T: Bt[c][h*F+f] (bf16)
  __shared__ unsigned short Ash[16][KROW];  // agg (bf16) per node
  __shared__ int s_idx[NW][64];
  __shared__ float4 s_w[NW][64];
  int t = threadIdx.x;
  for (int idx = t; idx < K * 64; idx += 64 * NW) {
    int c = idx & 63, hf = idx >> 6;
    Bt[c][hf] = f2bf(W[(size_t)hf * 64 + c]);
  }
  if constexpr (KP > K) {
    for (int idx = t; idx < 64 * (KP - K); idx += 64 * NW)
      Bt[idx / (KP - K)][K + idx % (KP - K)] = 0;
    for (int idx = t; idx < 16 * (KP - K); idx += 64 * NW)
      Ash[idx / (KP - K)][K + idx % (KP - K)] = 0;
  }
  __syncthreads();
  int wv = t >> 6, lane = t & 63;
  int lanef = lane & 31;  // dual-half (F=28) path
  int half = lane >> 5;
  int l15 = lane & 15, g8 = (lane >> 4) * 8;
  float bias_c = (wv < 4) ? bias[16 * wv + l15] : 0.f;
  for (int base = blockIdx.x * 16; base < N_N; base += gridDim.x * 16) {
#pragma unroll
    for (int rep = 0; rep < 2; ++rep) {
      int i = base + wv * 2 + rep;
      if (i < N_N) {
        int b = indptr[i], e = indptr[i + 1];
        float4 ad4 = *(const float4*)&al_d[i * 4];
        float4 as4 = *(const float4*)&al_s[i * 4];
        float es0 = lrelu(as4.x + ad4.x), es1 = lrelu(as4.y + ad4.y);
        float es2 = lrelu(as4.z + ad4.z), es3 = lrelu(as4.w + ad4.w);
        float m0 = es0, m1 = es1, m2 = es2, m3 = es3;
        float xself = (lane < F) ? xin[(size_t)i * F + lane] : 0.f;
        float a0 = xself, a1 = xself, a2 = xself, a3 = xself;  // self w = exp(0)
        if (F == F_IN && half) { a0 = 0.f; a1 = 0.f; a2 = 0.f; a3 = 0.f; }
        float pd0 = 0.f, pd1 = 0.f, pd2 = 0.f, pd3 = 0.f;
        for (int cb = b; cb < e; cb += 64) {
          int cnt = min(64, e - cb);
          bool act = (cb + lane) < e;
          int s = 0;
          float e0 = -1e30f, e1 = -1e30f, e2 = -1e30f, e3 = -1e30f;
          if (act) {
            s = csr[cb + lane];
            float4 a4 = *(const float4*)&al_s[s * 4];
            e0 = lrelu(a4.x + ad4.x);
            e1 = lrelu(a4.y + ad4.y);
            e2 = lrelu(a4.z + ad4.z);
            e3 = lrelu(a4.w + ad4.w);
          }
          float n0 = fmaxf(m0, wmax(e0)), n1 = fmaxf(m1, wmax(e1));
          float n2 = fmaxf(m2, wmax(e2)), n3 = fmaxf(m3, wmax(e3));
          float sc0 = __expf(m0 - n0), sc1 = __expf(m1 - n1);
          float sc2 = __expf(m2 - n2), sc3 = __expf(m3 - n3);
          a0 *= sc0; a1 *= sc1; a2 *= sc2; a3 *= sc3;
          pd0 *= sc0; pd1 *= sc1; pd2 *= sc2; pd3 *= sc3;
          m0 = n0; m1 = n1; m2 = n2; m3 = n3;
          float w0 = act ? __expf(e0 - m0) : 0.f;
          float w1 = act ? __expf(e1 - m1) : 0.f;
          float w2 = act ? __expf(e2 - m2) : 0.f;
          float w3 = act ? __expf(e3 - m3) : 0.f;
          pd0 += w0; pd1 += w1; pd2 += w2; pd3 += w3;
          s_idx[wv][lane] = s;
          s_w[wv][lane] = make_float4(w0, w1, w2, w3);
          if (F == F_IN) {
            for (int je = 0; je < cnt; je += 16) {
              int sj[8];
#pragma unroll
              for (int u = 0; u < 8; ++u) sj[u] = s_idx[wv][je + 2 * u + half];
              float xr[8];
#pragma unroll
              for (int u = 0; u < 8; ++u)
                xr[u] = (lanef < F_IN) ? xin[(size_t)sj[u] * F_IN + lanef] : 0.f;
#pragma unroll
              for (int u = 0; u < 8; ++u) {
                float4 w4 = s_w[wv][je + 2 * u + half];
                a0 = fmaf(w4.x, xr[u], a0);
                a1 = fmaf(w4.y, xr[u], a1);
                a2 = fmaf(w4.z, xr[u], a2);
                a3 = fmaf(w4.w, xr[u], a3);
              }
            }
          } else {
            for (int je = 0; je < cnt; je += 8) {
              int sj[8];
#pragma unroll
              for (int u = 0; u < 8; ++u) sj[u] = s_idx[wv][je + u];
              float xr[8];
#pragma unroll
              for (int u = 0; u < 8; ++u) xr[u] = xin[(size_t)sj[u] * F + lane];
#pragma unroll
              for (int u = 0; u < 8; ++u) {
                float4 w4 = s_w[wv][je + u];
                a0 = fmaf(w4.x, xr[u], a0);
                a1 = fmaf(w4.y, xr[u], a1);
                a2 = fmaf(w4.z, xr[u], a2);
                a3 = fmaf(w4.w, xr[u], a3);
              }
            }
          }
        }
        if (F == F_IN) {
          a0 += __shfl_xor(a0, 32, 64);
          a1 += __shfl_xor(a1, 32, 64);
          a2 += __shfl_xor(a2, 32, 64);
          a3 += __shfl_xor(a3, 32, 64);
        }
        float dn0 = wsum(pd0) + __expf(es0 - m0);
        float dn1 = wsum(pd1) + __expf(es1 - m1);
        float dn2 = wsum(pd2) + __expf(es2 - m2);
        float dn3 = wsum(pd3) + __expf(es3 - m3);
        a0 /= dn0; a1 /= dn1; a2 /= dn2; a3 /= dn3;
        if (lane < F) {
          int n = wv * 2 + rep;
          Ash[n][0 * F + lane] = f2bf(a0);
          Ash[n][1 * F + lane] = f2bf(a1);
          Ash[n][2 * F + lane] = f2bf(a2);
          Ash[n][3 * F + lane] = f2bf(a3);
        }
      }
    }
    __syncthreads();
    if (wv < 4) {  // MFMA epilogue: wave wv computes C cols [16wv,16wv+16)
      float4v c4 = {0.f, 0.f, 0.f, 0.f};
#pragma unroll
      for (int kk = 0; kk < KP; kk += 32) {
        short8v af = *(const short8v*)&Ash[l15][kk + g8];
        short8v bf = *(const short8v*)&Bt[16 * wv + l15][kk + g8];
        c4 = __builtin_amdgcn_mfma_f32_16x16x32_bf16(af, bf, c4, 0, 0, 0);
      }
#pragma unroll
      for (int reg = 0; reg < 4; ++reg) {
        int node = base + (g8 >> 1) + reg;  // row = (lane>>4)*4 + reg
        if (node < N_N) {
          float o = fmaxf(fmaf(c4[reg], 0.25f, bias_c), 0.f);
          xg[(size_t)node * 64 + 16 * wv + l15] = o;
        }
      }
    }
    __syncthreads();
  }
}

// ---- fused GIN: agg + MFMA MLP + residual + LN (+ logits / gate) ----
template <int NW, bool FUSE_AL, bool FUSE_GATE>
__global__ __launch_bounds__(64 * NW, 4) void k_gin(const int* __restrict__ indptr, const int* __restrict__ csr,
                                                    const float* __restrict__ xg, const float* __restrict__ w1,
                                                    const float* __restrict__ b1, const float* __restrict__ w2,
                                                    const float* __restrict__ b2, const float* __restrict__ lnw,
                                                    const float* __restrict__ lnb, float* __restrict__ xo,
                                                    const float* __restrict__ wsv, const float* __restrict__ wdv,
                                                    float* __restrict__ al_s, float* __restrict__ al_d,
                                                    const float* __restrict__ gw1, const float* __restrict__ gb1,
                                                    const float* __restrict__ gw2, const float* __restrict__ gb2,
                                                    float* __restrict__ gate) {
  constexpr int KR = 72;  // 64 + 8 pad (16B-aligned, bank-staggered)
  __shared__ unsigned short W1t[64][KR], W2t[64][KR];
  __shared__ unsigned short GW1t[FUSE_GATE ? 64 : 1][FUSE_GATE ? KR : 1];
  __shared__ unsigned short A1h[16][KR], A1l[16][KR], A2s[16][KR];
  __shared__ float A3[16][68];
  __shared__ unsigned short A4[FUSE_GATE ? 16 : 1][FUSE_GATE ? KR : 1];
  __shared__ float gred[4][16];
  int t = threadIdx.x;
  for (int idx = t; idx < 4096; idx += 64 * NW) {
    int k = idx >> 6, c = idx & 63;
    W1t[c][k] = f2bf(w1[idx]);
    W2t[c][k] = f2bf(w2[idx]);
    if constexpr (FUSE_GATE) GW1t[c][k] = f2bf(gw1[idx]);
  }
  __syncthreads();
  int wv = t >> 6, lane = t & 63;
  int l15 = lane & 15, g8 = (lane >> 4) * 8;
  float b1c = 0.f, b2c = 0.f, gb1c = 0.f, gw2c = 0.f;
  if (wv < 4) {
    b1c = b1[16 * wv + l15];
    b2c = b2[16 * wv + l15];
    if constexpr (FUSE_GATE) {
      gb1c = gb1[16 * wv + l15];
      gw2c = gw2[16 * wv + l15];
    }
  }
  float lnwv = lnw[lane], lnbv = lnb[lane];
  float wsr[4], wdr[4];
  if constexpr (FUSE_AL) {
#pragma unroll
    for (int h = 0; h < 4; ++h) {
      wsr[h] = wsv[h * 64 + lane];
      wdr[h] = wdv[h * 64 + lane];
    }
  }
  float gb2v = FUSE_GATE ? gb2[0] : 0.f;
  for (int base = blockIdx.x * 16; base < N_N; base += gridDim.x * 16) {
    float xis[2];
#pragma unroll
    for (int rep = 0; rep < 2; ++rep) {
      int i = base + wv * 2 + rep;
      if (i < N_N) {
        int b = indptr[i], e = indptr[i + 1];
        float xi = xg[(size_t)i * 64 + lane];
        xis[rep] = xi;
        float acc = xi;
        for (int j = b; j < e; j += 8) {
          int cj[8];
#pragma unroll
          for (int u = 0; u < 8; ++u) cj[u] = csr[min(j + u, e - 1)];
          float v[8];
#pragma unroll
          for (int u = 0; u < 8; ++u) v[u] = xg[(size_t)cj[u] * 64 + lane];
#pragma unroll
          for (int u = 0; u < 8; ++u) acc += (j + u) < e ? v[u] : 0.f;
        }
        int n = wv * 2 + rep;
        unsigned short hb = f2bf(acc);
        A1h[n][lane] = hb;
        A1l[n][lane] = f2bf(acc - bfs(hb));  // hi/lo split keeps MLP1 input ~f32
      }
    }
    __syncthreads();
    if (wv < 4) {  // MLP1: relu(A1 @ W1 + b1) -> A2 (bf16)
      float4v c4 = {0.f, 0.f, 0.f, 0.f};
#pragma unroll
      for (int kk = 0; kk < 64; kk += 32) {
        short8v bf = *(const short8v*)&W1t[16 * wv + l15][kk + g8];
        short8v ah = *(const short8v*)&A1h[l15][kk + g8];
        c4 = __builtin_amdgcn_mfma_f32_16x16x32_bf16(ah, bf, c4, 0, 0, 0);
        short8v al = *(const short8v*)&A1l[l15][kk + g8];
        c4 = __builtin_amdgcn_mfma_f32_16x16x32_bf16(al, bf, c4, 0, 0, 0);
      }
#pragma unroll
      for (int reg = 0; reg < 4; ++reg)
        A2s[(g8 >> 1) + reg][16 * wv + l15] = f2bf(fmaxf(c4[reg] + b1c, 0.f));
    }
    __syncthreads();
    if (wv < 4) {  // MLP2: A2 @ W2 + b2 -> A3 (f32)
      float4v c4 = {0.f, 0.f, 0.f, 0.f};
#pragma unroll
      for (int kk = 0; kk < 64; kk += 32) {
        short8v af = *(const short8v*)&A2s[l15][kk + g8];
        short8v bf = *(const short8v*)&W2t[16 * wv + l15][kk + g8];
        c4 = __builtin_amdgcn_mfma_f32_16x16x32_bf16(af, bf, c4, 0, 0, 0);
      }
#pragma unroll
      for (int reg = 0; reg < 4; ++reg) A3[(g8 >> 1) + reg][16 * wv + l15] = c4[reg] + b2c;
    }
    __syncthreads();
#pragma unroll
    for (int rep = 0; rep < 2; ++rep) {
      int i = base + wv * 2 + rep;
      if (i < N_N) {
        int n = wv * 2 + rep;
        float res = xis[rep] + A3[n][lane];
        float mu = wsum(res) * (1.f / 64.f);
        float d = res - mu;
        float var = wsum(d * d) * (1.f / 64.f);
        float xov = fmaf(d * rsqrtf(var + LN_EPS), lnwv, lnbv);
        xo[(size_t)i * 64 + lane] = xov;
        if constexpr (FUSE_AL) {
#pragma unroll
          for (int h = 0; h < HEADS; ++h) {
            float ss = wsum(xov * wsr[h]);
            float sd = wsum(xov * wdr[h]);
            if (lane == 0) {
              al_s[i * 4 + h] = ss;
              al_d[i * 4 + h] = sd;
            }
          }
        }
        if constexpr (FUSE_GATE) A4[n][lane] = f2bf(xov);
      }
    }
    if constexpr (FUSE_GATE) {
      __syncthreads();
      if (wv < 4) {  // gate hidden: relu(A4 @ GW1 + gb1), then dot with gw2
        float4v c4 = {0.f, 0.f, 0.f, 0.f};
#pragma unroll
        for (int kk = 0; kk < 64; kk += 32) {
          short8v af = *(const short8v*)&A4[l15][kk + g8];
          short8v bf = *(const short8v*)&GW1t[16 * wv + l15][kk + g8];
          c4 = __builtin_amdgcn_mfma_f32_16x16x32_bf16(af, bf, c4, 0, 0, 0);
        }
#pragma unroll
        for (int reg = 0; reg < 4; ++reg) {
          float m = fmaxf(c4[reg] + gb1c, 0.f) * gw2c;
          m += __shfl_xor(m, 1, 64);
          m += __shfl_xor(m, 2, 64);
          m += __shfl_xor(m, 4, 64);
          m += __shfl_xor(m, 8, 64);
          if (l15 == 0) gred[wv][(g8 >> 1) + reg] = m;
        }
      }
      __syncthreads();
      if (wv == 0 && lane < 16) {
        int node = base + lane;
        if (node < N_N)
          gate[node] = gred[0][lane] + gred[1][lane] + gred[2][lane] + gred[3][lane] + gb2v;
      }
      __syncthreads();
    }
  }
}

// ---------------- graph ranges via counting ----------------
__global__ __launch_bounds__(256) void k_gcount(const int* __restrict__ batch, int* gcnt) {
  int i = blockIdx.x * 256 + threadIdx.x;
  if (i < N_N) atomicAdd(&gcnt[batch[i]], 1);
}

__global__ __launch_bounds__(256) void k_gptr(const int* __restrict__ gcnt, int* __restrict__ gptr) {
  __shared__ int l[256];
  int t = threadIdx.x;
  int v = gcnt[t];
  l[t] = v;
  __syncthreads();
  for (int o = 1; o < 256; o <<= 1) {
    int a = (t >= o) ? l[t - o] : 0;
    __syncthreads();
    l[t] += a;
    __syncthreads();
  }
  gptr[t] = l[t] - v;
  if (t == 255) gptr[256] = l[255];
}

// ---------------- global attention pool ----------------
__global__ __launch_bounds__(256) void k_pool(const int* __restrict__ gptr, const float* __restrict__ gate,
                                              const float* __restrict__ x2, float* __restrict__ pooled) {
  int g = blockIdx.x;
  int t = threadIdx.x, wv = t >> 6, lane = t & 63;
  __shared__ float red[256];
  int b = gptr[g], e = gptr[g + 1];
  if (b == e) {
    if (t < 64) pooled[g * 64 + t] = 0.f;
    return;
  }
  float m = -1e30f;
  for (int j = b + t; j < e; j += 256) m = fmaxf(m, gate[j]);
  m = wmax(m);
  if (lane == 0) red[wv] = m;
  __syncthreads();
  m = fmaxf(fmaxf(red[0], red[1]), fmaxf(red[2], red[3]));
  __syncthreads();
  float dn = 0.f;
  for (int j = b + t; j < e; j += 256) dn += __expf(gate[j] - m);
  dn = wsum(dn);
  if (lane == 0) red[wv] = dn;
  __syncthreads();
  dn = red[0] + red[1] + red[2] + red[3];
  __syncthreads();
  float acc = 0.f;
  for (int j = b + wv; j < e; j += 4) acc = fmaf(__expf(gate[j] - m), x2[(size_t)j * 64 + lane], acc);
  red[t] = acc;
  __syncthreads();
  if (t < 64) pooled[g * 64 + t] = (red[t] + red[t + 64] + red[t + 128] + red[t + 192]) / dn;
}

// ---------------- head MLP ----------------
__global__ __launch_bounds__(128) void k_head(const float* __restrict__ pooled, const float* __restrict__ l1w,
                                              const float* __restrict__ l1b, const float* __restrict__ lnfw,
                                              const float* __restrict__ lnfb, const float* __restrict__ l2w,
                                              const float* __restrict__ l2b, float* __restrict__ out) {
  int g = blockIdx.x, t = threadIdx.x;
  __shared__ float pl[64], zl[128], red[2];
  if (t < 64) pl[t] = pooled[g * 64 + t];
  __syncthreads();
  float y = l1b[t];
#pragma unroll 8
  for (int k = 0; k < 64; ++k) y = fmaf(pl[k], l1w[k * 128 + t], y);
  int wv = t >> 6, lane = t & 63;
  float s = wsum(y);
  if (lane == 0) red[wv] = s;
  __syncthreads();
  float mu = (red[0] + red[1]) * (1.f / 128.f);
  float d = y - mu;
  __syncthreads();
  s = wsum(d * d);
  if (lane == 0) red[wv] = s;
  __syncthreads();
  float var = (red[0] + red[1]) * (1.f / 128.f);
  float z = fmaxf(fmaf(d * rsqrtf(var + LN_EPS), lnfw[t], lnfb[t]), 0.f);
  zl[t] = z;
  __syncthreads();
  if (t < 6) {
    float o = l2b[t];
    for (int k = 0; k < 128; ++k) o = fmaf(zl[k], l2w[k * 6 + t], o);
    out[g * 6 + t] = o;
  }
}

extern "C" void kernel_launch(void* const* d_in, const int* in_sizes, int n_in,
                              void* d_out, int out_size, void* d_ws, size_t ws_size,
                              hipStream_t stream) {
  const float* x = (const float*)d_in[0];
  const int* src = (const int*)d_in[1];
  const int* dst = (const int*)d_in[2];
  const int* batch = (const int*)d_in[3];
  const float* W1 = (const float*)d_in[4];
  const float* a1s = (const float*)d_in[5];
  const float* a1d = (const float*)d_in[6];
  const float* bg1 = (const float*)d_in[7];
  const float* m1w1 = (const float*)d_in[8];
  const float* m1b1 = (const float*)d_in[9];
  const float* m1w2 = (const float*)d_in[10];
  const float* m1b2 = (const float*)d_in[11];
  const float* ln1w = (const float*)d_in[12];
  const float* ln1b = (const float*)d_in[13];
  const float* W2 = (const float*)d_in[14];
  const float* a2s = (const float*)d_in[15];
  const float* a2d = (const float*)d_in[16];
  const float* bg2 = (const float*)d_in[17];
  const float* m2w1 = (const float*)d_in[18];
  const float* m2b1 = (const float*)d_in[19];
  const float* m2w2 = (const float*)d_in[20];
  const float* m2b2 = (const float*)d_in[21];
  const float* ln2w = (const float*)d_in[22];
  const float* ln2b = (const float*)d_in[23];
  const float* gw1 = (const float*)d_in[24];
  const float* gb1 = (const float*)d_in[25];
  const float* gw2 = (const float*)d_in[26];
  const float* gb2 = (const float*)d_in[27];
  const float* l1w = (const float*)d_in[28];
  const float* l1b = (const float*)d_in[29];
  const float* lnfw = (const float*)d_in[30];
  const float* lnfb = (const float*)d_in[31];
  const float* l2w = (const float*)d_in[32];
  const float* l2b = (const float*)d_in[33];
  float* out = (float*)d_out;

  char* ws = (char*)d_ws;
  size_t off = 0;
  auto alloc = [&](size_t bytes) -> void* {
    void* p = ws + off;
    off += (bytes + 255) & ~(size_t)255;
    return p;
  };
  int* indptr = (int*)alloc((N_N + 1) * sizeof(int));
  int* fill = (int*)alloc(N_N * sizeof(int));  // also degree
  int* csr = (int*)alloc((size_t)N_E * sizeof(int));
  int* bsum = (int*)alloc(512 * sizeof(int));
  int* bofs = (int*)alloc(512 * sizeof(int));
  int* gcnt = (int*)alloc(257 * sizeof(int));
  int* gptr = (int*)alloc(257 * sizeof(int));
  float* wsv = (float*)alloc(HEADS * 64 * sizeof(float));
  float* wdv = (float*)alloc(HEADS * 64 * sizeof(float));
  float* al_s = (float*)alloc((size_t)N_N * 4 * sizeof(float));
  float* al_d = (float*)alloc((size_t)N_N * 4 * sizeof(float));
  float* gate = (float*)alloc((size_t)N_N * sizeof(float));
  float* pooled = (float*)alloc(N_G * 64 * sizeof(float));
  float* xg = (float*)alloc((size_t)N_N * 64 * sizeof(float));
  float* xv = (float*)alloc((size_t)N_N * 64 * sizeof(float));
  (void)ws_size; (void)n_in; (void)in_sizes; (void)out_size;

  const int NBE = (N_E + 255) / 256;
  const int NBN = (N_N + 255) / 256;  // 391

  hipMemsetAsync(fill, 0, (size_t)N_N * sizeof(int), stream);
  hipMemsetAsync(gcnt, 0, 257 * sizeof(int), stream);
  k_deg<<<NBE, 256, 0, stream>>>(dst, fill);
  k_bsum<<<NBN, 256, 0, stream>>>(fill, bsum);
  k_scanb<<<1, 512, 0, stream>>>(bsum, bofs, NBN);
  k_indptr<<<NBN, 256, 0, stream>>>(fill, bofs, indptr);
  k_copyfill<<<NBN, 256, 0, stream>>>(indptr, fill);
  k_scatter<<<NBE, 256, 0, stream>>>(src, dst, fill, csr);
  k_sort<<<NBN, 256, 0, stream>>>(indptr, csr);
  k_gcount<<<NBN, 256, 0, stream>>>(batch, gcnt);
  k_gptr<<<1, 256, 0, stream>>>(gcnt, gptr);

  // ---- layer 1 ----
  k_avec<F_IN><<<1, 256, 0, stream>>>(W1, a1s, a1d, wsv, wdv);
  k_al<F_IN><<<2048, 256, 0, stream>>>(x, wsv, wdv, al_s, al_d);
  k_gat<F_IN, 8><<<2048, 512, 0, stream>>>(x, indptr, csr, al_s, al_d, W1, bg1, xg);
  k_avec<CH><<<1, 256, 0, stream>>>(W2, a2s, a2d, wsv, wdv);  // layer-2 logit vectors
  k_gin<8, true, false><<<2048, 512, 0, stream>>>(indptr, csr, xg, m1w1, m1b1, m1w2, m1b2, ln1w, ln1b,
                                                  xv, wsv, wdv, al_s, al_d, gw1, gb1, gw2, gb2, gate);
  // ---- layer 2 ----
  k_gat<CH, 8><<<2048, 512, 0, stream>>>(xv, indptr, csr, al_s, al_d, W2, bg2, xg);
  k_gin<8, false, true><<<2048, 512, 0, stream>>>(indptr, csr, xg, m2w1, m2b1, m2w2, m2b2, ln2w, ln2b,
                                                  xv, wsv, wdv, al_s, al_d, gw1, gb1, gw2, gb2, gate);
  // ---- pooling + head ----
  k_pool<<<N_G, 256, 0, stream>>>(gptr, gate, xv, pooled);
  k_head<<<N_G, 128, 0, stream>>>(pooled, l1w, l1b, lnfw, lnfb, l2w, l2b, out);
}

// Round 8
// 916.216 us; speedup vs baseline: 5.1038x; 1.1555x over previous
//
#include <hip/hip_runtime.h>

#define N_N 100000
#define N_E 1600000
#define N_G 256
#define F_IN 28
#define HEADS 4
#define CH 64
#define NEG 0.2f
#define LN_EPS 1e-5f

typedef __attribute__((ext_vector_type(8))) short short8v;   // 8 bf16
typedef __attribute__((ext_vector_type(4))) float float4v;   // MFMA acc

__device__ __forceinline__ float lrelu(float x) { return x > 0.f ? x : NEG * x; }

__device__ __forceinline__ float wsum(float v) {
#pragma unroll
  for (int o = 32; o > 0; o >>= 1) v += __shfl_xor(v, o, 64);
  return v;
}
__device__ __forceinline__ float wmax(float v) {
#pragma unroll
  for (int o = 32; o > 0; o >>= 1) v = fmaxf(v, __shfl_xor(v, o, 64));
  return v;
}
__device__ __forceinline__ int wsumi(int v) {
#pragma unroll
  for (int o = 32; o > 0; o >>= 1) v += __shfl_xor(v, o, 64);
  return v;
}

// bf16 helpers (storage-only compression in LDS)
__device__ __forceinline__ float bfs(unsigned short u) {
  return __uint_as_float((unsigned)u << 16);
}
__device__ __forceinline__ unsigned short f2bf(float v) {
  unsigned u = __float_as_uint(v);
  return (unsigned short)((u + 0x7fff + ((u >> 16) & 1)) >> 16);  // RNE
}

// ---------------- CSR build ----------------
__global__ __launch_bounds__(256) void k_deg(const int* __restrict__ dst, int* deg) {
  int e = blockIdx.x * 256 + threadIdx.x;
  if (e < N_E) atomicAdd(&deg[dst[e]], 1);
}

__global__ __launch_bounds__(256) void k_bsum(const int* __restrict__ deg, int* __restrict__ bsum) {
  __shared__ int l[4];
  int t = threadIdx.x;
  int i = blockIdx.x * 256 + t;
  int v = (i < N_N) ? deg[i] : 0;
  int s = wsumi(v);
  if ((t & 63) == 0) l[t >> 6] = s;
  __syncthreads();
  if (t == 0) bsum[blockIdx.x] = l[0] + l[1] + l[2] + l[3];
}

__global__ __launch_bounds__(512) void k_scanb(const int* __restrict__ bsum, int* __restrict__ bofs, int nb) {
  __shared__ int l[512];
  int t = threadIdx.x;
  int v = (t < nb) ? bsum[t] : 0;
  l[t] = v;
  __syncthreads();
  for (int o = 1; o < 512; o <<= 1) {
    int a = (t >= o) ? l[t - o] : 0;
    __syncthreads();
    l[t] += a;
    __syncthreads();
  }
  if (t < nb) bofs[t] = l[t] - v;  // exclusive
}

// writes indptr AND fill (copyfill fused)
__global__ __launch_bounds__(256) void k_indptr(const int* __restrict__ deg, const int* __restrict__ bofs,
                                                int* __restrict__ indptr, int* __restrict__ fill) {
  __shared__ int l[256];
  int t = threadIdx.x;
  int i = blockIdx.x * 256 + t;
  int v = (i < N_N) ? deg[i] : 0;
  l[t] = v;
  __syncthreads();
  for (int o = 1; o < 256; o <<= 1) {
    int a = (t >= o) ? l[t - o] : 0;
    __syncthreads();
    l[t] += a;
    __syncthreads();
  }
  if (i < N_N) {
    int p = bofs[blockIdx.x] + l[t] - v;
    indptr[i] = p;
    fill[i] = p;
  }
  if (i == 0) indptr[N_N] = N_E;
}

__global__ __launch_bounds__(256) void k_scatter(const int* __restrict__ src, const int* __restrict__ dst,
                                                 int* fill, int* __restrict__ csr) {
  int e = blockIdx.x * 256 + threadIdx.x;
  if (e < N_E) {
    int d = dst[e];
    int p = atomicAdd(&fill[d], 1);
    csr[p] = src[e];
  }
}

// deterministic order within each bucket: wave-parallel rank sort.
// Values (src ids) determine final positions; duplicates are interchangeable,
// so csr content is deterministic regardless of scatter order.
__global__ __launch_bounds__(256) void k_sortw(const int* __restrict__ indptr, int* __restrict__ csr) {
  int wv = threadIdx.x >> 6, lane = threadIdx.x & 63;
  int i = blockIdx.x * 4 + wv;
  if (i >= N_N) return;
  int b = indptr[i], e = indptr[i + 1];
  int deg = e - b;
  if (deg <= 1) return;
  if (deg <= 64) {
    int v = (lane < deg) ? csr[b + lane] : 0x7fffffff;
    int rank = 0;
    for (int j = 0; j < deg; ++j) {
      int vj = __shfl(v, j, 64);
      rank += ((vj < v) || (vj == v && j < lane)) ? 1 : 0;
    }
    if (lane < deg) csr[b + rank] = v;
  } else if (lane == 0) {  // rare fallback
    for (int j = b + 1; j < e; ++j) {
      int key = csr[j];
      int k = j - 1;
      while (k >= b && csr[k] > key) { csr[k + 1] = csr[k]; --k; }
      csr[k + 1] = key;
    }
  }
}

// ---------------- attention logits: al = x @ (W_h a_h) ----------------
template <int F>
__global__ __launch_bounds__(256) void k_avec(const float* __restrict__ W, const float* __restrict__ as_,
                                              const float* __restrict__ ad_, float* __restrict__ wsv,
                                              float* __restrict__ wdv) {
  int idx = blockIdx.x * 256 + threadIdx.x;
  if (idx >= HEADS * F) return;
  int h = idx / F, f = idx % F;
  float s = 0.f, d = 0.f;
  for (int c = 0; c < 64; ++c) {
    float w = W[(h * F + f) * 64 + c];
    s = fmaf(w, as_[h * 64 + c], s);
    d = fmaf(w, ad_[h * 64 + c], d);
  }
  wsv[idx] = s;
  wdv[idx] = d;
}

// LDS-staged, shuffle-free: 64 nodes/block, thread (n,h) computes 2 dots.
template <int F>
__global__ __launch_bounds__(256) void k_al2(const float* __restrict__ xin, const float* __restrict__ wsv,
                                             const float* __restrict__ wdv, float* __restrict__ al_s,
                                             float* __restrict__ al_d) {
  constexpr int FP = (F % 2 == 0) ? F + 1 : F;  // odd row stride
  __shared__ float xl[64][FP];
  __shared__ float wsl[HEADS][F], wdl[HEADS][F];
  int t = threadIdx.x;
  for (int idx = t; idx < HEADS * F; idx += 256) {
    wsl[idx / F][idx % F] = wsv[idx];
    wdl[idx / F][idx % F] = wdv[idx];
  }
  int base = blockIdx.x * 64;
  for (int idx = t; idx < 64 * F; idx += 256) {
    int n = idx / F, f = idx % F;
    int i = base + n;
    xl[n][f] = (i < N_N) ? xin[(size_t)i * F + f] : 0.f;  // coalesced
  }
  __syncthreads();
  int n = t >> 2, h = t & 3;
  int i = base + n;
  if (i < N_N) {
    float s = 0.f, d = 0.f;
#pragma unroll
    for (int f = 0; f < F; ++f) {
      float xv = xl[n][f];
      s = fmaf(xv, wsl[h][f], s);
      d = fmaf(xv, wdl[h][f], d);
    }
    al_s[i * 4 + h] = s;
    al_d[i * 4 + h] = d;
  }
}

// ---------------- fused GAT layer ----------------
// 16 nodes per block iteration: 8 waves aggregate 2 nodes each (online softmax,
// unroll-8 gather), stage agg to LDS (bf16), then 4 waves apply W via MFMA.
// out[i,c] = relu( bias[c] + 0.25 * sum_h sum_f aggF[i,h,f] * W[h,f,c] )
template <int F, int NW>
__global__ __launch_bounds__(64 * NW, 4) void k_gat(const float* __restrict__ xin, const int* __restrict__ indptr,
                                                    const int* __restrict__ csr, const float* __restrict__ al_s,
                                                    const float* __restrict__ al_d, const float* __restrict__ W,
                                                    const float* __restrict__ bias, float* __restrict__ xg) {
  constexpr int K = HEADS * F;        // 256 / 112
  constexpr int KP = (K + 31) & ~31;  // MFMA K coverage: 256 / 128
  constexpr int KROW = KP + 8;        // 16B-aligned rows, bank-staggered
  __shared__ unsigned short Bt[64][KROW];   // W^T: Bt[c][h*F+f] (bf16)
  __shared__ unsigned short Ash[16][KROW];  // agg (bf16) per node
  __shared__ int s_idx[NW][64];
  __shared__ float4 s_w[NW][64];
  int t = threadIdx.x;
  for (int idx = t; idx < K * 64; idx += 64 * NW) {
    int c = idx & 63, hf = idx >> 6;
    Bt[c][hf] = f2bf(W[(size_t)hf * 64 + c]);
  }
  if constexpr (KP > K) {
    for (int idx = t; idx < 64 * (KP - K); idx += 64 * NW)
      Bt[idx / (KP - K)][K + idx % (KP - K)] = 0;
    for (int idx = t; idx < 16 * (KP - K); idx += 64 * NW)
      Ash[idx / (KP - K)][K + idx % (KP - K)] = 0;
  }
  __syncthreads();
  int wv = t >> 6, lane = t & 63;
  int lanef = lane & 31;  // dual-half (F=28) path
  int half = lane >> 5;
  int l15 = lane & 15, g8 = (lane >> 4) * 8;
  float bias_c = (wv < 4) ? bias[16 * wv + l15] : 0.f;
  for (int base = blockIdx.x * 16; base < N_N; base += gridDim.x * 16) {
#pragma unroll
    for (int rep = 0; rep < 2; ++rep) {
      int i = base + wv * 2 + rep;
      if (i < N_N) {
        int b = indptr[i], e = indptr[i + 1];
        float4 ad4 = *(const float4*)&al_d[i * 4];
        float4 as4 = *(const float4*)&al_s[i * 4];
        float es0 = lrelu(as4.x + ad4.x), es1 = lrelu(as4.y + ad4.y);
        float es2 = lrelu(as4.z + ad4.z), es3 = lrelu(as4.w + ad4.w);
        float m0 = es0, m1 = es1, m2 = es2, m3 = es3;
        float xself = (lane < F) ? xin[(size_t)i * F + lane] : 0.f;
        float a0 = xself, a1 = xself, a2 = xself, a3 = xself;  // self w = exp(0)
        if (F == F_IN && half) { a0 = 0.f; a1 = 0.f; a2 = 0.f; a3 = 0.f; }
        float pd0 = 0.f, pd1 = 0.f, pd2 = 0.f, pd3 = 0.f;
        for (int cb = b; cb < e; cb += 64) {
          int cnt = min(64, e - cb);
          bool act = (cb + lane) < e;
          int s = 0;
          float e0 = -1e30f, e1 = -1e30f, e2 = -1e30f, e3 = -1e30f;
          if (act) {
            s = csr[cb + lane];
            float4 a4 = *(const float4*)&al_s[s * 4];
            e0 = lrelu(a4.x + ad4.x);
            e1 = lrelu(a4.y + ad4.y);
            e2 = lrelu(a4.z + ad4.z);
            e3 = lrelu(a4.w + ad4.w);
          }
          float n0 = fmaxf(m0, wmax(e0)), n1 = fmaxf(m1, wmax(e1));
          float n2 = fmaxf(m2, wmax(e2)), n3 = fmaxf(m3, wmax(e3));
          float sc0 = __expf(m0 - n0), sc1 = __expf(m1 - n1);
          float sc2 = __expf(m2 - n2), sc3 = __expf(m3 - n3);
          a0 *= sc0; a1 *= sc1; a2 *= sc2; a3 *= sc3;
          pd0 *= sc0; pd1 *= sc1; pd2 *= sc2; pd3 *= sc3;
          m0 = n0; m1 = n1; m2 = n2; m3 = n3;
          float w0 = act ? __expf(e0 - m0) : 0.f;
          float w1 = act ? __expf(e1 - m1) : 0.f;
          float w2 = act ? __expf(e2 - m2) : 0.f;
          float w3 = act ? __expf(e3 - m3) : 0.f;
          pd0 += w0; pd1 += w1; pd2 += w2; pd3 += w3;
          s_idx[wv][lane] = s;
          s_w[wv][lane] = make_float4(w0, w1, w2, w3);
          if (F == F_IN) {
            for (int je = 0; je < cnt; je += 16) {
              int sj[8];
#pragma unroll
              for (int u = 0; u < 8; ++u) sj[u] = s_idx[wv][je + 2 * u + half];
              float xr[8];
#pragma unroll
              for (int u = 0; u < 8; ++u)
                xr[u] = (lanef < F_IN) ? xin[(size_t)sj[u] * F_IN + lanef] : 0.f;
#pragma unroll
              for (int u = 0; u < 8; ++u) {
                float4 w4 = s_w[wv][je + 2 * u + half];
                a0 = fmaf(w4.x, xr[u], a0);
                a1 = fmaf(w4.y, xr[u], a1);
                a2 = fmaf(w4.z, xr[u], a2);
                a3 = fmaf(w4.w, xr[u], a3);
              }
            }
          } else {
            for (int je = 0; je < cnt; je += 8) {
              int sj[8];
#pragma unroll
              for (int u = 0; u < 8; ++u) sj[u] = s_idx[wv][je + u];
              float xr[8];
#pragma unroll
              for (int u = 0; u < 8; ++u) xr[u] = xin[(size_t)sj[u] * F + lane];
#pragma unroll
              for (int u = 0; u < 8; ++u) {
                float4 w4 = s_w[wv][je + u];
                a0 = fmaf(w4.x, xr[u], a0);
                a1 = fmaf(w4.y, xr[u], a1);
                a2 = fmaf(w4.z, xr[u], a2);
                a3 = fmaf(w4.w, xr[u], a3);
              }
            }
          }
        }
        if (F == F_IN) {
          a0 += __shfl_xor(a0, 32, 64);
          a1 += __shfl_xor(a1, 32, 64);
          a2 += __shfl_xor(a2, 32, 64);
          a3 += __shfl_xor(a3, 32, 64);
        }
        float dn0 = wsum(pd0) + __expf(es0 - m0);
        float dn1 = wsum(pd1) + __expf(es1 - m1);
        float dn2 = wsum(pd2) + __expf(es2 - m2);
        float dn3 = wsum(pd3) + __expf(es3 - m3);
        a0 /= dn0; a1 /= dn1; a2 /= dn2; a3 /= dn3;
        if (lane < F) {
          int n = wv * 2 + rep;
          Ash[n][0 * F + lane] = f2bf(a0);
          Ash[n][1 * F + lane] = f2bf(a1);
          Ash[n][2 * F + lane] = f2bf(a2);
          Ash[n][3 * F + lane] = f2bf(a3);
        }
      }
    }
    __syncthreads();
    if (wv < 4) {  // MFMA epilogue: wave wv computes C cols [16wv,16wv+16)
      float4v c4 = {0.f, 0.f, 0.f, 0.f};
#pragma unroll
      for (int kk = 0; kk < KP; kk += 32) {
        short8v af = *(const short8v*)&Ash[l15][kk + g8];
        short8v bf = *(const short8v*)&Bt[16 * wv + l15][kk + g8];
        c4 = __builtin_amdgcn_mfma_f32_16x16x32_bf16(af, bf, c4, 0, 0, 0);
      }
#pragma unroll
      for (int reg = 0; reg < 4; ++reg) {
        int node = base + (g8 >> 1) + reg;  // row = (lane>>4)*4 + reg
        if (node < N_N) {
          float o = fmaxf(fmaf(c4[reg], 0.25f, bias_c), 0.f);
          xg[(size_t)node * 64 + 16 * wv + l15] = o;
        }
      }
    }
    __syncthreads();
  }
}

// ---- fused GIN: agg + MFMA MLP + residual + LN (+ logits / gate) ----
template <int NW, bool FUSE_AL, bool FUSE_GATE>
__global__ __launch_bounds__(64 * NW, 4) void k_gin(const int* __restrict__ indptr, const int* __restrict__ csr,
                                                    const float* __restrict__ xg, const float* __restrict__ w1,
                                                    const float* __restrict__ b1, const float* __restrict__ w2,
                                                    const float* __restrict__ b2, const float* __restrict__ lnw,
                                                    const float* __restrict__ lnb, float* __restrict__ xo,
                                                    const float* __restrict__ wsv, const float* __restrict__ wdv,
                                                    float* __restrict__ al_s, float* __restrict__ al_d,
                                                    const float* __restrict__ gw1, const float* __restrict__ gb1,
                                                    const float* __restrict__ gw2, const float* __restrict__ gb2,
                                                    float* __restrict__ gate) {
  constexpr int KR = 72;  // 64 + 8 pad (16B-aligned, bank-staggered)
  __shared__ unsigned short W1t[64][KR], W2t[64][KR];
  __shared__ unsigned short GW1t[FUSE_GATE ? 64 : 1][FUSE_GATE ? KR : 1];
  __shared__ unsigned short WVt[FUSE_AL ? 16 : 1][FUSE_AL ? KR : 1];
  __shared__ unsigned short A1h[16][KR], A1l[16][KR], A2s[16][KR];
  __shared__ float A3[16][68];
  __shared__ unsigned short A4[FUSE_GATE ? 16 : 1][FUSE_GATE ? KR : 1];
  __shared__ float gred[4][16];
  int t = threadIdx.x;
  for (int idx = t; idx < 4096; idx += 64 * NW) {
    int k = idx >> 6, c = idx & 63;
    W1t[c][k] = f2bf(w1[idx]);
    W2t[c][k] = f2bf(w2[idx]);
    if constexpr (FUSE_GATE) GW1t[c][k] = f2bf(gw1[idx]);
  }
  if constexpr (FUSE_AL) {
    for (int idx = t; idx < 16 * 64; idx += 64 * NW) {
      int j = idx >> 6, k = idx & 63;
      float v = (j < 4) ? wsv[j * 64 + k] : (j < 8 ? wdv[(j - 4) * 64 + k] : 0.f);
      WVt[j][k] = f2bf(v);
    }
  }
  __syncthreads();
  int wv = t >> 6, lane = t & 63;
  int l15 = lane & 15, g8 = (lane >> 4) * 8;
  float b1c = 0.f, b2c = 0.f, gb1c = 0.f, gw2c = 0.f;
  if (wv < 4) {
    b1c = b1[16 * wv + l15];
    b2c = b2[16 * wv + l15];
    if constexpr (FUSE_GATE) {
      gb1c = gb1[16 * wv + l15];
      gw2c = gw2[16 * wv + l15];
    }
  }
  float lnwv = lnw[lane], lnbv = lnb[lane];
  float gb2v = FUSE_GATE ? gb2[0] : 0.f;
  for (int base = blockIdx.x * 16; base < N_N; base += gridDim.x * 16) {
    float xis[2];
#pragma unroll
    for (int rep = 0; rep < 2; ++rep) {
      int i = base + wv * 2 + rep;
      if (i < N_N) {
        int b = indptr[i], e = indptr[i + 1];
        float xi = xg[(size_t)i * 64 + lane];
        xis[rep] = xi;
        float acc = xi;
        for (int j = b; j < e; j += 8) {
          int cj[8];
#pragma unroll
          for (int u = 0; u < 8; ++u) cj[u] = csr[min(j + u, e - 1)];
          float v[8];
#pragma unroll
          for (int u = 0; u < 8; ++u) v[u] = xg[(size_t)cj[u] * 64 + lane];
#pragma unroll
          for (int u = 0; u < 8; ++u) acc += (j + u) < e ? v[u] : 0.f;
        }
        int n = wv * 2 + rep;
        unsigned short hb = f2bf(acc);
        A1h[n][lane] = hb;
        A1l[n][lane] = f2bf(acc - bfs(hb));  // hi/lo split keeps MLP1 input ~f32
      }
    }
    __syncthreads();
    if (wv < 4) {  // MLP1: relu(A1 @ W1 + b1) -> A2 (bf16)
      float4v c4 = {0.f, 0.f, 0.f, 0.f};
#pragma unroll
      for (int kk = 0; kk < 64; kk += 32) {
        short8v bf = *(const short8v*)&W1t[16 * wv + l15][kk + g8];
        short8v ah = *(const short8v*)&A1h[l15][kk + g8];
        c4 = __builtin_amdgcn_mfma_f32_16x16x32_bf16(ah, bf, c4, 0, 0, 0);
        short8v al = *(const short8v*)&A1l[l15][kk + g8];
        c4 = __builtin_amdgcn_mfma_f32_16x16x32_bf16(al, bf, c4, 0, 0, 0);
      }
#pragma unroll
      for (int reg = 0; reg < 4; ++reg)
        A2s[(g8 >> 1) + reg][16 * wv + l15] = f2bf(fmaxf(c4[reg] + b1c, 0.f));
    }
    __syncthreads();
    if (wv < 4) {  // MLP2: A2 @ W2 + b2 -> A3 (f32)
      float4v c4 = {0.f, 0.f, 0.f, 0.f};
#pragma unroll
      for (int kk = 0; kk < 64; kk += 32) {
        short8v af = *(const short8v*)&A2s[l15][kk + g8];
        short8v bf = *(const short8v*)&W2t[16 * wv + l15][kk + g8];
        c4 = __builtin_amdgcn_mfma_f32_16x16x32_bf16(af, bf, c4, 0, 0, 0);
      }
#pragma unroll
      for (int reg = 0; reg < 4; ++reg) A3[(g8 >> 1) + reg][16 * wv + l15] = c4[reg] + b2c;
    }
    __syncthreads();
#pragma unroll
    for (int rep = 0; rep < 2; ++rep) {
      int i = base + wv * 2 + rep;
      if (i < N_N) {
        int n = wv * 2 + rep;
        float res = xis[rep] + A3[n][lane];
        float mu = wsum(res) * (1.f / 64.f);
        float d = res - mu;
        float var = wsum(d * d) * (1.f / 64.f);
        float xov = fmaf(d * rsqrtf(var + LN_EPS), lnwv, lnbv);
        xo[(size_t)i * 64 + lane] = xov;
        if constexpr (FUSE_AL) {  // stage xov hi/lo for the logit MFMA
          unsigned short hb = f2bf(xov);
          A1h[n][lane] = hb;
          A1l[n][lane] = f2bf(xov - bfs(hb));
        }
        if constexpr (FUSE_GATE) A4[n][lane] = f2bf(xov);
      }
    }
    if constexpr (FUSE_AL) {
      __syncthreads();
      if (wv == 0) {  // [16 nodes x 64] @ [64 x 16 logit cols] (8 used)
        float4v c4 = {0.f, 0.f, 0.f, 0.f};
#pragma unroll
        for (int kk = 0; kk < 64; kk += 32) {
          short8v bf = *(const short8v*)&WVt[l15][kk + g8];
          short8v ah = *(const short8v*)&A1h[l15][kk + g8];
          c4 = __builtin_amdgcn_mfma_f32_16x16x32_bf16(ah, bf, c4, 0, 0, 0);
          short8v al = *(const short8v*)&A1l[l15][kk + g8];
          c4 = __builtin_amdgcn_mfma_f32_16x16x32_bf16(al, bf, c4, 0, 0, 0);
        }
#pragma unroll
        for (int reg = 0; reg < 4; ++reg) {
          int node = base + (g8 >> 1) + reg;
          if (node < N_N) {
            if (l15 < 4) al_s[node * 4 + l15] = c4[reg];
            else if (l15 < 8) al_d[node * 4 + (l15 - 4)] = c4[reg];
          }
        }
      }
      __syncthreads();  // before next tile overwrites A1h/A1l
    }
    if constexpr (FUSE_GATE) {
      __syncthreads();
      if (wv < 4) {  // gate hidden: relu(A4 @ GW1 + gb1), then dot with gw2
        float4v c4 = {0.f, 0.f, 0.f, 0.f};
#pragma unroll
        for (int kk = 0; kk < 64; kk += 32) {
          short8v af = *(const short8v*)&A4[l15][kk + g8];
          short8v bf = *(const short8v*)&GW1t[16 * wv + l15][kk + g8];
          c4 = __builtin_amdgcn_mfma_f32_16x16x32_bf16(af, bf, c4, 0, 0, 0);
        }
#pragma unroll
        for (int reg = 0; reg < 4; ++reg) {
          float m = fmaxf(c4[reg] + gb1c, 0.f) * gw2c;
          m += __shfl_xor(m, 1, 64);
          m += __shfl_xor(m, 2, 64);
          m += __shfl_xor(m, 4, 64);
          m += __shfl_xor(m, 8, 64);
          if (l15 == 0) gred[wv][(g8 >> 1) + reg] = m;
        }
      }
      __syncthreads();
      if (wv == 0 && lane < 16) {
        int node = base + lane;
        if (node < N_N)
          gate[node] = gred[0][lane] + gred[1][lane] + gred[2][lane] + gred[3][lane] + gb2v;
      }
      __syncthreads();
    }
  }
}

// ---------------- graph ranges via counting ----------------
__global__ __launch_bounds__(256) void k_gcount(const int* __restrict__ batch, int* gcnt) {
  int i = blockIdx.x * 256 + threadIdx.x;
  if (i < N_N) atomicAdd(&gcnt[batch[i]], 1);
}

__global__ __launch_bounds__(256) void k_gptr(const int* __restrict__ gcnt, int* __restrict__ gptr) {
  __shared__ int l[256];
  int t = threadIdx.x;
  int v = gcnt[t];
  l[t] = v;
  __syncthreads();
  for (int o = 1; o < 256; o <<= 1) {
    int a = (t >= o) ? l[t - o] : 0;
    __syncthreads();
    l[t] += a;
    __syncthreads();
  }
  gptr[t] = l[t] - v;
  if (t == 255) gptr[256] = l[255];
}

// ---------------- global attention pool ----------------
__global__ __launch_bounds__(256) void k_pool(const int* __restrict__ gptr, const float* __restrict__ gate,
                                              const float* __restrict__ x2, float* __restrict__ pooled) {
  int g = blockIdx.x;
  int t = threadIdx.x, wv = t >> 6, lane = t & 63;
  __shared__ float red[256];
  int b = gptr[g], e = gptr[g + 1];
  if (b == e) {
    if (t < 64) pooled[g * 64 + t] = 0.f;
    return;
  }
  float m = -1e30f;
  for (int j = b + t; j < e; j += 256) m = fmaxf(m, gate[j]);
  m = wmax(m);
  if (lane == 0) red[wv] = m;
  __syncthreads();
  m = fmaxf(fmaxf(red[0], red[1]), fmaxf(red[2], red[3]));
  __syncthreads();
  float dn = 0.f;
  for (int j = b + t; j < e; j += 256) dn += __expf(gate[j] - m);
  dn = wsum(dn);
  if (lane == 0) red[wv] = dn;
  __syncthreads();
  dn = red[0] + red[1] + red[2] + red[3];
  __syncthreads();
  float acc = 0.f;
  for (int j = b + wv; j < e; j += 4) acc = fmaf(__expf(gate[j] - m), x2[(size_t)j * 64 + lane], acc);
  red[t] = acc;
  __syncthreads();
  if (t < 64) pooled[g * 64 + t] = (red[t] + red[t + 64] + red[t + 128] + red[t + 192]) / dn;
}

// ---------------- head MLP ----------------
__global__ __launch_bounds__(128) void k_head(const float* __restrict__ pooled, const float* __restrict__ l1w,
                                              const float* __restrict__ l1b, const float* __restrict__ lnfw,
                                              const float* __restrict__ lnfb, const float* __restrict__ l2w,
                                              const float* __restrict__ l2b, float* __restrict__ out) {
  int g = blockIdx.x, t = threadIdx.x;
  __shared__ float pl[64], zl[128], red[2];
  if (t < 64) pl[t] = pooled[g * 64 + t];
  __syncthreads();
  float y = l1b[t];
#pragma unroll 8
  for (int k = 0; k < 64; ++k) y = fmaf(pl[k], l1w[k * 128 + t], y);
  int wv = t >> 6, lane = t & 63;
  float s = wsum(y);
  if (lane == 0) red[wv] = s;
  __syncthreads();
  float mu = (red[0] + red[1]) * (1.f / 128.f);
  float d = y - mu;
  __syncthreads();
  s = wsum(d * d);
  if (lane == 0) red[wv] = s;
  __syncthreads();
  float var = (red[0] + red[1]) * (1.f / 128.f);
  float z = fmaxf(fmaf(d * rsqrtf(var + LN_EPS), lnfw[t], lnfb[t]), 0.f);
  zl[t] = z;
  __syncthreads();
  if (t < 6) {
    float o = l2b[t];
    for (int k = 0; k < 128; ++k) o = fmaf(zl[k], l2w[k * 6 + t], o);
    out[g * 6 + t] = o;
  }
}

extern "C" void kernel_launch(void* const* d_in, const int* in_sizes, int n_in,
                              void* d_out, int out_size, void* d_ws, size_t ws_size,
                              hipStream_t stream) {
  const float* x = (const float*)d_in[0];
  const int* src = (const int*)d_in[1];
  const int* dst = (const int*)d_in[2];
  const int* batch = (const int*)d_in[3];
  const float* W1 = (const float*)d_in[4];
  const float* a1s = (const float*)d_in[5];
  const float* a1d = (const float*)d_in[6];
  const float* bg1 = (const float*)d_in[7];
  const float* m1w1 = (const float*)d_in[8];
  const float* m1b1 = (const float*)d_in[9];
  const float* m1w2 = (const float*)d_in[10];
  const float* m1b2 = (const float*)d_in[11];
  const float* ln1w = (const float*)d_in[12];
  const float* ln1b = (const float*)d_in[13];
  const float* W2 = (const float*)d_in[14];
  const float* a2s = (const float*)d_in[15];
  const float* a2d = (const float*)d_in[16];
  const float* bg2 = (const float*)d_in[17];
  const float* m2w1 = (const float*)d_in[18];
  const float* m2b1 = (const float*)d_in[19];
  const float* m2w2 = (const float*)d_in[20];
  const float* m2b2 = (const float*)d_in[21];
  const float* ln2w = (const float*)d_in[22];
  const float* ln2b = (const float*)d_in[23];
  const float* gw1 = (const float*)d_in[24];
  const float* gb1 = (const float*)d_in[25];
  const float* gw2 = (const float*)d_in[26];
  const float* gb2 = (const float*)d_in[27];
  const float* l1w = (const float*)d_in[28];
  const float* l1b = (const float*)d_in[29];
  const float* lnfw = (const float*)d_in[30];
  const float* lnfb = (const float*)d_in[31];
  const float* l2w = (const float*)d_in[32];
  const float* l2b = (const float*)d_in[33];
  float* out = (float*)d_out;

  char* ws = (char*)d_ws;
  size_t off = 0;
  auto alloc = [&](size_t bytes) -> void* {
    void* p = ws + off;
    off += (bytes + 255) & ~(size_t)255;
    return p;
  };
  int* indptr = (int*)alloc((N_N + 1) * sizeof(int));
  int* fill = (int*)alloc(N_N * sizeof(int));  // also degree
  int* csr = (int*)alloc((size_t)N_E * sizeof(int));
  int* bsum = (int*)alloc(512 * sizeof(int));
  int* bofs = (int*)alloc(512 * sizeof(int));
  int* gcnt = (int*)alloc(257 * sizeof(int));
  int* gptr = (int*)alloc(257 * sizeof(int));
  float* wsv = (float*)alloc(HEADS * 64 * sizeof(float));
  float* wdv = (float*)alloc(HEADS * 64 * sizeof(float));
  float* al_s = (float*)alloc((size_t)N_N * 4 * sizeof(float));
  float* al_d = (float*)alloc((size_t)N_N * 4 * sizeof(float));
  float* gate = (float*)alloc((size_t)N_N * sizeof(float));
  float* pooled = (float*)alloc(N_G * 64 * sizeof(float));
  float* xg = (float*)alloc((size_t)N_N * 64 * sizeof(float));
  float* xv = (float*)alloc((size_t)N_N * 64 * sizeof(float));
  (void)ws_size; (void)n_in; (void)in_sizes; (void)out_size;

  const int NBE = (N_E + 255) / 256;
  const int NBN = (N_N + 255) / 256;  // 391

  hipMemsetAsync(fill, 0, (size_t)N_N * sizeof(int), stream);
  hipMemsetAsync(gcnt, 0, 257 * sizeof(int), stream);
  k_deg<<<NBE, 256, 0, stream>>>(dst, fill);
  k_bsum<<<NBN, 256, 0, stream>>>(fill, bsum);
  k_scanb<<<1, 512, 0, stream>>>(bsum, bofs, NBN);
  k_indptr<<<NBN, 256, 0, stream>>>(fill, bofs, indptr, fill);
  k_scatter<<<NBE, 256, 0, stream>>>(src, dst, fill, csr);
  k_sortw<<<(N_N + 3) / 4, 256, 0, stream>>>(indptr, csr);
  k_gcount<<<NBN, 256, 0, stream>>>(batch, gcnt);
  k_gptr<<<1, 256, 0, stream>>>(gcnt, gptr);

  // ---- layer 1 ----
  k_avec<F_IN><<<1, 256, 0, stream>>>(W1, a1s, a1d, wsv, wdv);
  k_al2<F_IN><<<(N_N + 63) / 64, 256, 0, stream>>>(x, wsv, wdv, al_s, al_d);
  k_gat<F_IN, 8><<<2048, 512, 0, stream>>>(x, indptr, csr, al_s, al_d, W1, bg1, xg);
  k_avec<CH><<<1, 256, 0, stream>>>(W2, a2s, a2d, wsv, wdv);  // layer-2 logit vectors
  k_gin<8, true, false><<<2048, 512, 0, stream>>>(indptr, csr, xg, m1w1, m1b1, m1w2, m1b2, ln1w, ln1b,
                                                  xv, wsv, wdv, al_s, al_d, gw1, gb1, gw2, gb2, gate);
  // ---- layer 2 ----
  k_gat<CH, 8><<<2048, 512, 0, stream>>>(xv, indptr, csr, al_s, al_d, W2, bg2, xg);
  k_gin<8, false, true><<<2048, 512, 0, stream>>>(indptr, csr, xg, m2w1, m2b1, m2w2, m2b2, ln2w, ln2b,
                                                  xv, wsv, wdv, al_s, al_d, gw1, gb1, gw2, gb2, gate);
  // ---- pooling + head ----
  k_pool<<<N_G, 256, 0, stream>>>(gptr, gate, xv, pooled);
  k_head<<<N_G, 128, 0, stream>>>(pooled, l1w, l1b, lnfw, lnfb, l2w, l2b, out);
}